// Round 2
// baseline (261.192 us; speedup 1.0000x reference)
//
#include <hip/hip_runtime.h>
#include <math.h>

#define Bsz 512
#define INsz 128
#define Nn 256
#define Ww 64
#define Rr 4
#define Uu 256
#define OUTsz 128
#define IFACEsz 471
#define XDIM 384   /* IN + W*R */
#define KL 640     /* XDIM + U */
#define G4 1024    /* 4*U */

__device__ __forceinline__ float sigf(float x){ return 1.0f/(1.0f+expf(-x)); }
__device__ __forceinline__ float softplusf_(float x){ return fmaxf(x,0.0f) + log1pf(expf(-fabsf(x))); }
__device__ __forceinline__ float4 f4fma(float s, float4 a, float4 acc){
  acc.x += s*a.x; acc.y += s*a.y; acc.z += s*a.z; acc.w += s*a.w; return acc;
}

// ---------------- pack kernels ---------------------------------------------
__global__ __launch_bounds__(256) void k_packX(
  const float* __restrict__ inputs, const float* __restrict__ rvp,
  const float* __restrict__ hp, float* __restrict__ X)
{
  const int b = blockIdx.x, t = threadIdx.x;
  if (t < 160){
    int c4 = t*4;
    float4 v;
    if (c4 < INsz)      v = *reinterpret_cast<const float4*>(inputs + (size_t)b*INsz + c4);
    else if (c4 < XDIM) v = *reinterpret_cast<const float4*>(rvp + (size_t)b*(Ww*Rr) + (c4-INsz));
    else                v = *reinterpret_cast<const float4*>(hp + (size_t)b*Uu + (c4-XDIM));
    *reinterpret_cast<float4*>(X + (size_t)b*KL + c4) = v;
  }
}

__global__ __launch_bounds__(256) void k_packW(
  const float* __restrict__ Wk, const float* __restrict__ Wr, float* __restrict__ W)
{
  const int row = blockIdx.x, t = threadIdx.x;
  const float* src = (row < XDIM) ? (Wk + (size_t)row*G4) : (Wr + (size_t)(row-XDIM)*G4);
  float4 v = *reinterpret_cast<const float4*>(src + t*4);
  *reinterpret_cast<float4*>(W + (size_t)row*G4 + t*4) = v;
}

__global__ __launch_bounds__(256) void k_packWi(
  const float* __restrict__ Wi, float* __restrict__ Wip)
{
  const int k = blockIdx.x, t = threadIdx.x;
  for (int j=t; j<512; j+=256)
    Wip[(size_t)k*512 + j] = (j < IFACEsz) ? Wi[(size_t)k*IFACEsz + j] : 0.0f;
}

// ---------------- K1: LSTM GEMM z = X * W (K-split 2) ----------------------
// grid (32 batch-tiles, 8 col-tiles, 2 k-splits), 256 threads.
__global__ __launch_bounds__(256) void k_lstm2(
  const float* __restrict__ X, const float* __restrict__ W, float* __restrict__ zpart)
{
  const int t = threadIdx.x;
  const int tx = t & 31, ty = t >> 5;      // tx: 32 col-quads, ty: 8 batch-pairs
  const int b0 = blockIdx.x*16;
  const int col = blockIdx.y*128 + tx*4;
  const int k0 = blockIdx.z*320;
  __shared__ float Xs[16][68];
  float4 a0 = {0,0,0,0}, a1 = {0,0,0,0};
  const int bl0 = ty*2, bl1 = ty*2+1;
  for (int kc = 0; kc < 320; kc += 64){
    {
      int rr = t >> 4, cc = (t & 15)*4;
      *reinterpret_cast<float4*>(&Xs[rr][cc]) =
        *reinterpret_cast<const float4*>(X + (size_t)(b0+rr)*KL + k0 + kc + cc);
    }
    __syncthreads();
    const float* Wp = W + (size_t)(k0+kc)*G4 + col;
    #pragma unroll 8
    for (int kk=0; kk<64; ++kk){
      float4 w4 = *reinterpret_cast<const float4*>(Wp + (size_t)kk*G4);
      float x0 = Xs[bl0][kk], x1 = Xs[bl1][kk];
      a0 = f4fma(x0, w4, a0);
      a1 = f4fma(x1, w4, a1);
    }
    __syncthreads();
  }
  size_t base = ((size_t)blockIdx.z*Bsz + b0)*G4 + col;
  *reinterpret_cast<float4*>(zpart + base + (size_t)bl0*G4) = a0;
  *reinterpret_cast<float4*>(zpart + base + (size_t)bl1*G4) = a1;
}

__global__ __launch_bounds__(256) void k_lstm_fin(
  const float* __restrict__ zpart, const float* __restrict__ bl,
  const float* __restrict__ cprev, float* __restrict__ h_out)
{
  const int b = blockIdx.x, t = threadIdx.x;
  const size_t o = (size_t)b*G4 + t;
  const size_t sp = (size_t)Bsz*G4;
  float zi = zpart[o]       + zpart[o+sp]       + bl[t];
  float zf = zpart[o+256]   + zpart[o+sp+256]   + bl[t+256];
  float zc = zpart[o+512]   + zpart[o+sp+512]   + bl[t+512];
  float zo = zpart[o+768]   + zpart[o+sp+768]   + bl[t+768];
  float c = sigf(zf)*cprev[(size_t)b*Uu+t] + sigf(zi)*tanhf(zc);
  float h = sigf(zo)*tanhf(c);
  h = fminf(fmaxf(h,-20.0f),20.0f);
  h_out[(size_t)b*Uu+t] = h;
}

// ---------------- K2a: interface GEMM v = h * Wip --------------------------
// grid (32 batch-tiles, 8 col-tiles), 256 threads.
__global__ __launch_bounds__(256) void k_ifgemm(
  const float* __restrict__ h_ws, const float* __restrict__ Wip, float* __restrict__ v_ws)
{
  const int t = threadIdx.x;
  const int tx = t & 15, ty = t >> 4;
  const int b0 = blockIdx.x*16;
  const int col = blockIdx.y*64 + tx*4;
  __shared__ float Hs[16][68];
  float4 acc = {0,0,0,0};
  for (int kc = 0; kc < Uu; kc += 64){
    {
      int rr = t >> 4, cc = (t & 15)*4;
      *reinterpret_cast<float4*>(&Hs[rr][cc]) =
        *reinterpret_cast<const float4*>(h_ws + (size_t)(b0+rr)*Uu + kc + cc);
    }
    __syncthreads();
    const float* Wp = Wip + (size_t)kc*512 + col;
    #pragma unroll 8
    for (int kk=0; kk<64; ++kk){
      float4 w4 = *reinterpret_cast<const float4*>(Wp + (size_t)kk*512);
      acc = f4fma(Hs[ty][kk], w4, acc);
    }
    __syncthreads();
  }
  *reinterpret_cast<float4*>(v_ws + (size_t)(b0+ty)*512 + col) = acc;
}

// ---------------- K2b: interface logic -------------------------------------
__global__ __launch_bounds__(256) void k_iface2(
  const float* __restrict__ v_ws, const float* __restrict__ bi,
  const float* __restrict__ usage, const float* __restrict__ wwp,
  const float* __restrict__ wrp, const float* __restrict__ prec,
  const float* __restrict__ M,
  float* __restrict__ ww_ws, float* __restrict__ er_ws, float* __restrict__ wv_ws,
  float* __restrict__ rk_ws, float* __restrict__ krn_ws, float* __restrict__ rstr_ws,
  float* __restrict__ rm_ws, float* __restrict__ P_ws, float* __restrict__ Q_ws)
{
  const int b = blockIdx.x, t = threadIdx.x;
  __shared__ float vl[IFACEsz];
  __shared__ float wkey[Ww];
  __shared__ float ul[Nn], sul[Nn], cpl[Nn], red[Nn];
  __shared__ float scal[8];
  for (int j=t; j<IFACEsz; j+=256) vl[j] = v_ws[(size_t)b*512 + j] + bi[j];
  __syncthreads();
  if (t < Ww){
    wkey[t] = vl[260+t];
    er_ws[b*Ww+t] = sigf(vl[325+t]);
    wv_ws[b*Ww+t] = vl[389+t];
  }
  rk_ws[b*Ww*Rr + t] = vl[t];
  if (t < Rr){
    rstr_ws[b*Rr+t] = 1.0f + softplusf_(vl[256+t]);
    float ssum = 0.0f;
    for (int w=0;w<Ww;++w){ float v = vl[w*Rr+t]; ssum += v*v; }
    krn_ws[b*Rr+t] = sqrtf(ssum);
    float q0=vl[459+t], q1=vl[463+t], q2=vl[467+t];
    float mm = fmaxf(q0, fmaxf(q1,q2));
    float e0=expf(q0-mm), e1=expf(q1-mm), e2=expf(q2-mm);
    float inv = 1.0f/(e0+e1+e2);
    rm_ws[b*12 + t]     = e0*inv;
    rm_ws[b*12 + 4 + t] = e1*inv;
    rm_ws[b*12 + 8 + t] = e2*inv;
    scal[4+t] = sigf(vl[453+t]);
  }
  if (t == 0){
    scal[0] = 1.0f + softplusf_(vl[324]);
    scal[1] = sigf(vl[457]);
    scal[2] = sigf(vl[458]);
    float ssum=0.0f;
    for (int w=0;w<Ww;++w){ float v=vl[260+w]; ssum += v*v; }
    scal[3] = sqrtf(ssum);
  }
  __syncthreads();
  float4 wr4 = *reinterpret_cast<const float4*>(wrp + ((size_t)b*Nn + t)*Rr);
  float psi = (1.0f - scal[4]*wr4.x)*(1.0f - scal[5]*wr4.y)
            * (1.0f - scal[6]*wr4.z)*(1.0f - scal[7]*wr4.w);
  float us = usage[b*Nn+t], wp = wwp[b*Nn+t];
  float u = (us + wp - us*wp)*psi;
  ul[t] = u;
  __syncthreads();
  int rank = 0;
  for (int m=0;m<Nn;++m){
    float um = ul[m];
    rank += (um < u || (um == u && m < t)) ? 1 : 0;
  }
  sul[rank] = u;
  __syncthreads();
  cpl[t] = sul[t];
  __syncthreads();
  for (int d=1; d<Nn; d<<=1){
    float a = cpl[t];
    float m_ = (t >= d) ? cpl[t-d] : 1.0f;
    __syncthreads();
    cpl[t] = a*m_;
    __syncthreads();
  }
  float cpexcl = (rank == 0) ? 1.0f : cpl[rank-1];
  float alloc = (1.0f - u)*cpexcl;
  const float* Mrow = M + ((size_t)b*Nn + t)*Ww;
  float dot=0.0f, nrm=0.0f;
  #pragma unroll 4
  for (int w=0;w<Ww;w+=4){
    float4 m4 = *reinterpret_cast<const float4*>(Mrow + w);
    dot += m4.x*wkey[w] + m4.y*wkey[w+1] + m4.z*wkey[w+2] + m4.w*wkey[w+3];
    nrm += m4.x*m4.x + m4.y*m4.y + m4.z*m4.z + m4.w*m4.w;
  }
  float sim = dot/(sqrtf(nrm)*scal[3] + 1e-6f);
  float sc = scal[0]*sim;
  red[t] = sc; __syncthreads();
  for (int st=128; st>0; st>>=1){ if (t<st) red[t] = fmaxf(red[t], red[t+st]); __syncthreads(); }
  float mx = red[0]; __syncthreads();
  float e = expf(sc - mx);
  red[t] = e; __syncthreads();
  for (int st=128; st>0; st>>=1){ if (t<st) red[t] += red[t+st]; __syncthreads(); }
  float cw = e/red[0];
  float ww = scal[2]*(scal[1]*alloc + (1.0f - scal[1])*cw);
  ww_ws[b*Nn+t] = ww;
  __syncthreads();
  float pr = prec[b*Nn+t];
  float wrv[4] = {wr4.x, wr4.y, wr4.z, wr4.w};
  #pragma unroll
  for (int r=0;r<Rr;++r){
    red[t] = pr*wrv[r]; __syncthreads();
    for (int st=128; st>0; st>>=1){ if (t<st) red[t]+=red[t+st]; __syncthreads(); }
    if (t==0) P_ws[b*Rr+r] = red[0];
    __syncthreads();
    red[t] = ww*wrv[r]; __syncthreads();
    for (int st=128; st>0; st>>=1){ if (t<st) red[t]+=red[t+st]; __syncthreads(); }
    if (t==0) Q_ws[b*Rr+r] = red[0];
    __syncthreads();
  }
}

// ---------------- K3: fused link row+col products (single pass) ------------
__global__ __launch_bounds__(256) void k_link(
  const float* __restrict__ link, const float* __restrict__ wrp,
  const float* __restrict__ ww_ws,
  float* __restrict__ rowA, float* __restrict__ rowC,
  float* __restrict__ colA, float* __restrict__ colC, float* __restrict__ diag)
{
  const int b = blockIdx.x, t = threadIdx.x;
  __shared__ float4 wrl4[Nn];
  __shared__ float wwl[Nn];
  __shared__ float4 cred[4][Nn];
  wrl4[t] = *reinterpret_cast<const float4*>(wrp + ((size_t)b*Nn + t)*Rr);
  wwl[t]  = ww_ws[(size_t)b*Nn + t];
  __syncthreads();
  const int mc = (t & 63)*4;   // this thread's 4 columns
  const int g  = t >> 6;       // row group (row ≡ g mod 4)
  float4 wm0 = wrl4[mc], wm1 = wrl4[mc+1], wm2 = wrl4[mc+2], wm3 = wrl4[mc+3];
  float wwm0 = wwl[mc], wwm1 = wwl[mc+1], wwm2 = wwl[mc+2], wwm3 = wwl[mc+3];
  float4 z = {0,0,0,0};
  float4 cA0=z,cA1=z,cA2=z,cA3=z, cC0=z,cC1=z,cC2=z,cC3=z;
  const float* Lb = link + (size_t)b*Nn*Nn;
  for (int i=0;i<64;++i){
    const int n = i*4 + g;
    float4 l4 = *reinterpret_cast<const float4*>(Lb + (size_t)n*Nn + mc);
    float4 wn = wrl4[n];
    float wwn = wwl[n];
    float4 wnw; wnw.x = wwn*wn.x; wnw.y = wwn*wn.y; wnw.z = wwn*wn.z; wnw.w = wwn*wn.w;
    // row partials (this lane's 4 cols)
    float4 ra = z, rc = z;
    ra = f4fma(l4.x, wm0, ra); ra = f4fma(l4.y, wm1, ra);
    ra = f4fma(l4.z, wm2, ra); ra = f4fma(l4.w, wm3, ra);
    rc = f4fma(l4.x*wwm0, wm0, rc); rc = f4fma(l4.y*wwm1, wm1, rc);
    rc = f4fma(l4.z*wwm2, wm2, rc); rc = f4fma(l4.w*wwm3, wm3, rc);
    // col accumulators
    cA0 = f4fma(l4.x, wn, cA0); cA1 = f4fma(l4.y, wn, cA1);
    cA2 = f4fma(l4.z, wn, cA2); cA3 = f4fma(l4.w, wn, cA3);
    cC0 = f4fma(l4.x, wnw, cC0); cC1 = f4fma(l4.y, wnw, cC1);
    cC2 = f4fma(l4.z, wnw, cC2); cC3 = f4fma(l4.w, wnw, cC3);
    // 64-lane reduce of ra, rc
    #pragma unroll
    for (int m=1; m<64; m<<=1){
      ra.x += __shfl_xor(ra.x, m); ra.y += __shfl_xor(ra.y, m);
      ra.z += __shfl_xor(ra.z, m); ra.w += __shfl_xor(ra.w, m);
      rc.x += __shfl_xor(rc.x, m); rc.y += __shfl_xor(rc.y, m);
      rc.z += __shfl_xor(rc.z, m); rc.w += __shfl_xor(rc.w, m);
    }
    if ((t & 63) == 0){
      *reinterpret_cast<float4*>(rowA + ((size_t)b*Nn + n)*Rr) = ra;
      *reinterpret_cast<float4*>(rowC + ((size_t)b*Nn + n)*Rr) = rc;
    }
    if (n >= mc && n < mc+4){
      float d = (n-mc==0)?l4.x : (n-mc==1)?l4.y : (n-mc==2)?l4.z : l4.w;
      diag[(size_t)b*Nn + n] = d;
    }
  }
  // reduce col accumulators across the 4 row-groups
  cred[g][mc] = cA0; cred[g][mc+1] = cA1; cred[g][mc+2] = cA2; cred[g][mc+3] = cA3;
  __syncthreads();
  {
    float4 s = cred[0][t];
    float4 s1 = cred[1][t], s2 = cred[2][t], s3 = cred[3][t];
    s.x += s1.x+s2.x+s3.x; s.y += s1.y+s2.y+s3.y; s.z += s1.z+s2.z+s3.z; s.w += s1.w+s2.w+s3.w;
    *reinterpret_cast<float4*>(colA + ((size_t)b*Nn + t)*Rr) = s;
  }
  __syncthreads();
  cred[g][mc] = cC0; cred[g][mc+1] = cC1; cred[g][mc+2] = cC2; cred[g][mc+3] = cC3;
  __syncthreads();
  {
    float4 s = cred[0][t];
    float4 s1 = cred[1][t], s2 = cred[2][t], s3 = cred[3][t];
    s.x += s1.x+s2.x+s3.x; s.y += s1.y+s2.y+s3.y; s.z += s1.z+s2.z+s3.z; s.w += s1.w+s2.w+s3.w;
    *reinterpret_cast<float4*>(colC + ((size_t)b*Nn + t)*Rr) = s;
  }
}

// ---------------- K4: fwd/bwd, read content addressing, wr ----------------
__global__ __launch_bounds__(256) void k_readw(
  const float* __restrict__ M, const float* __restrict__ ww_ws,
  const float* __restrict__ er_ws, const float* __restrict__ wv_ws,
  const float* __restrict__ rk_ws, const float* __restrict__ krn_ws,
  const float* __restrict__ rstr_ws, const float* __restrict__ rm_ws,
  const float* __restrict__ P_ws, const float* __restrict__ Q_ws,
  const float* __restrict__ rowA, const float* __restrict__ rowC,
  const float* __restrict__ colA, const float* __restrict__ colC,
  const float* __restrict__ diag, const float* __restrict__ wrp,
  const float* __restrict__ prec, float* __restrict__ wr_out)
{
  const int b = blockIdx.x, t = threadIdx.x;
  __shared__ float rkl[Ww*Rr];
  __shared__ float erl[Ww], wvl[Ww];
  __shared__ float red[Nn];
  rkl[t] = rk_ws[b*Ww*Rr + t];
  if (t < Ww){ erl[t] = er_ws[b*Ww+t]; wvl[t] = wv_ws[b*Ww+t]; }
  __syncthreads();
  const float ww = ww_ws[b*Nn+t];
  const float pr = prec[b*Nn+t];
  const float dg = diag[b*Nn+t];
  float4 wr4 = *reinterpret_cast<const float4*>(wrp + ((size_t)b*Nn+t)*Rr);
  const float Lnn = (1.0f - 2.0f*ww)*dg + ww*pr;
  float4 rA = *reinterpret_cast<const float4*>(rowA + ((size_t)b*Nn+t)*Rr);
  float4 rC = *reinterpret_cast<const float4*>(rowC + ((size_t)b*Nn+t)*Rr);
  float4 cA = *reinterpret_cast<const float4*>(colA + ((size_t)b*Nn+t)*Rr);
  float4 cC = *reinterpret_cast<const float4*>(colC + ((size_t)b*Nn+t)*Rr);
  float4 Pv = *reinterpret_cast<const float4*>(P_ws + b*Rr);
  float4 Qv = *reinterpret_cast<const float4*>(Q_ws + b*Rr);
  float fwdv[4], bwdv[4];
  fwdv[0] = (1.0f-ww)*rA.x - rC.x + ww*Pv.x - Lnn*wr4.x;
  fwdv[1] = (1.0f-ww)*rA.y - rC.y + ww*Pv.y - Lnn*wr4.y;
  fwdv[2] = (1.0f-ww)*rA.z - rC.z + ww*Pv.z - Lnn*wr4.z;
  fwdv[3] = (1.0f-ww)*rA.w - rC.w + ww*Pv.w - Lnn*wr4.w;
  bwdv[0] = (1.0f-ww)*cA.x - cC.x + pr*Qv.x - Lnn*wr4.x;
  bwdv[1] = (1.0f-ww)*cA.y - cC.y + pr*Qv.y - Lnn*wr4.y;
  bwdv[2] = (1.0f-ww)*cA.z - cC.z + pr*Qv.z - Lnn*wr4.z;
  bwdv[3] = (1.0f-ww)*cA.w - cC.w + pr*Qv.w - Lnn*wr4.w;
  const float* Mrow = M + ((size_t)b*Nn + t)*Ww;
  float s0=0,s1=0,s2=0,s3=0, nrm=0;
  #pragma unroll 4
  for (int w=0;w<Ww;w+=4){
    float4 m4 = *reinterpret_cast<const float4*>(Mrow + w);
    float mvs[4] = {m4.x, m4.y, m4.z, m4.w};
    #pragma unroll
    for (int i=0;i<4;++i){
      int w_ = w+i;
      float mn = mvs[i]*(1.0f - ww*erl[w_]) + ww*wvl[w_];
      nrm += mn*mn;
      float4 k4 = *reinterpret_cast<const float4*>(&rkl[w_*4]);
      s0 += mn*k4.x; s1 += mn*k4.y; s2 += mn*k4.z; s3 += mn*k4.w;
    }
  }
  float mnorm = sqrtf(nrm);
  float4 kn = *reinterpret_cast<const float4*>(krn_ws + b*Rr);
  float4 rs = *reinterpret_cast<const float4*>(rstr_ws + b*Rr);
  float aa[4];
  aa[0] = rs.x*(s0/(mnorm*kn.x + 1e-6f));
  aa[1] = rs.y*(s1/(mnorm*kn.y + 1e-6f));
  aa[2] = rs.z*(s2/(mnorm*kn.z + 1e-6f));
  aa[3] = rs.w*(s3/(mnorm*kn.w + 1e-6f));
  float cr[4];
  #pragma unroll
  for (int r=0;r<4;++r){
    red[t]=aa[r]; __syncthreads();
    for (int st=128; st>0; st>>=1){ if (t<st) red[t]=fmaxf(red[t],red[t+st]); __syncthreads(); }
    float mx = red[0]; __syncthreads();
    float e = expf(aa[r]-mx);
    red[t]=e; __syncthreads();
    for (int st=128; st>0; st>>=1){ if (t<st) red[t]+=red[t+st]; __syncthreads(); }
    cr[r] = e/red[0]; __syncthreads();
  }
  float wro[4];
  #pragma unroll
  for (int r=0;r<4;++r){
    float m0 = rm_ws[b*12 + r];
    float m1 = rm_ws[b*12 + 4 + r];
    float m2 = rm_ws[b*12 + 8 + r];
    wro[r] = m0*bwdv[r] + m1*cr[r] + m2*fwdv[r];
  }
  float4 o4; o4.x=wro[0]; o4.y=wro[1]; o4.z=wro[2]; o4.w=wro[3];
  *reinterpret_cast<float4*>(wr_out + ((size_t)b*Nn+t)*Rr) = o4;
}

// ---------------- K5a: read vectors ----------------------------------------
__global__ __launch_bounds__(256) void k_rv(
  const float* __restrict__ M, const float* __restrict__ ww_ws,
  const float* __restrict__ er_ws, const float* __restrict__ wv_ws,
  const float* __restrict__ wr_ws, float* __restrict__ rv_ws)
{
  const int b = blockIdx.x, t = threadIdx.x;
  __shared__ float wwl[Nn];
  __shared__ float wrl[Nn][4];
  __shared__ float erl[Ww], wvl[Ww];
  wwl[t] = ww_ws[b*Nn+t];
  {
    float4 w4 = *reinterpret_cast<const float4*>(wr_ws + ((size_t)b*Nn+t)*Rr);
    wrl[t][0]=w4.x; wrl[t][1]=w4.y; wrl[t][2]=w4.z; wrl[t][3]=w4.w;
  }
  if (t < Ww){ erl[t]=er_ws[b*Ww+t]; wvl[t]=wv_ws[b*Ww+t]; }
  __syncthreads();
  const int w = t & 63, r = t >> 6;
  const float er_w = erl[w], wv_w = wvl[w];
  float acc = 0.0f;
  #pragma unroll 4
  for (int n=0;n<Nn;++n){
    float m = M[((size_t)b*Nn + n)*Ww + w];
    float wwn = wwl[n];
    float mn = m*(1.0f - wwn*er_w) + wwn*wv_w;
    acc += mn*wrl[n][r];
  }
  rv_ws[(size_t)b*(Ww*Rr) + w*Rr + r] = acc;
}

// ---------------- K5b: output GEMM -----------------------------------------
// grid (32 batch-tiles, 2 col-tiles), 256 threads.
__global__ __launch_bounds__(256) void k_final(
  const float* __restrict__ h_ws, const float* __restrict__ rv_ws,
  const float* __restrict__ Wo, const float* __restrict__ bo,
  float* __restrict__ out)
{
  const int t = threadIdx.x;
  const int tx = t & 15, ty = t >> 4;
  const int b0 = blockIdx.x*16;
  const int col = blockIdx.y*64 + tx*4;
  __shared__ float Cs[16][68];
  float4 acc = {0,0,0,0};
  for (int kc = 0; kc < 512; kc += 64){
    {
      int rr = t >> 4, cc = (t & 15)*4;
      const float* src = (kc < Uu)
        ? (h_ws  + (size_t)(b0+rr)*Uu + kc + cc)
        : (rv_ws + (size_t)(b0+rr)*(Ww*Rr) + (kc-Uu) + cc);
      *reinterpret_cast<float4*>(&Cs[rr][cc]) = *reinterpret_cast<const float4*>(src);
    }
    __syncthreads();
    const float* Wp = Wo + (size_t)kc*OUTsz + col;
    #pragma unroll 8
    for (int kk=0; kk<64; ++kk){
      float4 w4 = *reinterpret_cast<const float4*>(Wp + (size_t)kk*OUTsz);
      acc = f4fma(Cs[ty][kk], w4, acc);
    }
    __syncthreads();
  }
  float4 b4 = *reinterpret_cast<const float4*>(bo + col);
  acc.x = fminf(fmaxf(acc.x + b4.x, -20.0f), 20.0f);
  acc.y = fminf(fmaxf(acc.y + b4.y, -20.0f), 20.0f);
  acc.z = fminf(fmaxf(acc.z + b4.z, -20.0f), 20.0f);
  acc.w = fminf(fmaxf(acc.w + b4.w, -20.0f), 20.0f);
  *reinterpret_cast<float4*>(out + (size_t)(b0+ty)*OUTsz + col) = acc;
}

extern "C" void kernel_launch(void* const* d_in, const int* in_sizes, int n_in,
                              void* d_out, int out_size, void* d_ws, size_t ws_size,
                              hipStream_t stream)
{
  const float* inputs = (const float*)d_in[0];
  const float* M      = (const float*)d_in[1];
  const float* usage  = (const float*)d_in[2];
  const float* link   = (const float*)d_in[3];
  const float* prec   = (const float*)d_in[4];
  const float* wwp    = (const float*)d_in[5];
  const float* wrp    = (const float*)d_in[6];
  const float* hp     = (const float*)d_in[7];
  const float* cp     = (const float*)d_in[8];
  const float* rvp    = (const float*)d_in[9];
  const float* Wk     = (const float*)d_in[10];
  const float* Wr     = (const float*)d_in[11];
  const float* bl     = (const float*)d_in[12];
  const float* Wi     = (const float*)d_in[13];
  const float* bi     = (const float*)d_in[14];
  const float* Wo     = (const float*)d_in[15];
  const float* bo     = (const float*)d_in[16];

  float* ws = (float*)d_ws;
  float* X_ws    = ws;                                  // 512*640
  float* W_ws    = X_ws   + (size_t)Bsz*KL;             // 640*1024
  float* zpart   = W_ws   + (size_t)KL*G4;              // 2*512*1024
  float* Wip     = zpart  + (size_t)2*Bsz*G4;           // 256*512
  float* v_ws    = Wip    + (size_t)Uu*512;             // 512*512
  float* h_ws    = v_ws   + (size_t)Bsz*512;            // 512*256
  float* ww_ws   = h_ws   + (size_t)Bsz*Uu;
  float* er_ws   = ww_ws  + (size_t)Bsz*Nn;
  float* wv_ws   = er_ws  + (size_t)Bsz*Ww;
  float* rk_ws   = wv_ws  + (size_t)Bsz*Ww;
  float* krn_ws  = rk_ws  + (size_t)Bsz*Ww*Rr;
  float* rstr_ws = krn_ws + (size_t)Bsz*Rr;
  float* rm_ws   = rstr_ws+ (size_t)Bsz*Rr;
  float* P_ws    = rm_ws  + (size_t)Bsz*3*Rr;
  float* Q_ws    = P_ws   + (size_t)Bsz*Rr;
  float* rowA    = Q_ws   + (size_t)Bsz*Rr;
  float* rowC    = rowA   + (size_t)Bsz*Nn*Rr;
  float* colA    = rowC   + (size_t)Bsz*Nn*Rr;
  float* colC    = colA   + (size_t)Bsz*Nn*Rr;
  float* diag    = colC   + (size_t)Bsz*Nn*Rr;
  float* wr_ws   = diag   + (size_t)Bsz*Nn;
  float* rv_ws   = wr_ws  + (size_t)Bsz*Nn*Rr;

  k_packX<<<dim3(Bsz), dim3(256), 0, stream>>>(inputs, rvp, hp, X_ws);
  k_packW<<<dim3(KL), dim3(256), 0, stream>>>(Wk, Wr, W_ws);
  k_packWi<<<dim3(Uu), dim3(256), 0, stream>>>(Wi, Wip);
  k_lstm2<<<dim3(32,8,2), dim3(256), 0, stream>>>(X_ws, W_ws, zpart);
  k_lstm_fin<<<dim3(Bsz), dim3(256), 0, stream>>>(zpart, bl, cp, h_ws);
  k_ifgemm<<<dim3(32,8), dim3(256), 0, stream>>>(h_ws, Wip, v_ws);
  k_iface2<<<dim3(Bsz), dim3(256), 0, stream>>>(v_ws, bi, usage, wwp, wrp, prec, M,
      ww_ws, er_ws, wv_ws, rk_ws, krn_ws, rstr_ws, rm_ws, P_ws, Q_ws);
  k_link<<<dim3(Bsz), dim3(256), 0, stream>>>(link, wrp, ww_ws, rowA, rowC, colA, colC, diag);
  k_readw<<<dim3(Bsz), dim3(256), 0, stream>>>(M, ww_ws, er_ws, wv_ws, rk_ws, krn_ws,
      rstr_ws, rm_ws, P_ws, Q_ws, rowA, rowC, colA, colC, diag, wrp, prec, wr_ws);
  k_rv<<<dim3(Bsz), dim3(256), 0, stream>>>(M, ww_ws, er_ws, wv_ws, wr_ws, rv_ws);
  k_final<<<dim3(32,2), dim3(256), 0, stream>>>(h_ws, rv_ws, Wo, bo, (float*)d_out);
}

// Round 3
// 254.086 us; speedup vs baseline: 1.0280x; 1.0280x over previous
//
#include <hip/hip_runtime.h>
#include <math.h>

#define Bsz 512
#define INsz 128
#define Nn 256
#define Ww 64
#define Rr 4
#define Uu 256
#define OUTsz 128
#define IFACEsz 471
#define XDIM 384   /* IN + W*R */
#define KL 640     /* XDIM + U */
#define G4 1024    /* 4*U */

__device__ __forceinline__ float sigf(float x){ return 1.0f/(1.0f+expf(-x)); }
__device__ __forceinline__ float softplusf_(float x){ return fmaxf(x,0.0f) + log1pf(expf(-fabsf(x))); }
__device__ __forceinline__ float4 f4fma(float s, float4 a, float4 acc){
  acc.x += s*a.x; acc.y += s*a.y; acc.z += s*a.z; acc.w += s*a.w; return acc;
}
__device__ __forceinline__ float4 f4add(float4 a, float4 b){
  a.x+=b.x; a.y+=b.y; a.z+=b.z; a.w+=b.w; return a;
}
__device__ __forceinline__ float4 f4max(float4 a, float4 b){
  a.x=fmaxf(a.x,b.x); a.y=fmaxf(a.y,b.y); a.z=fmaxf(a.z,b.z); a.w=fmaxf(a.w,b.w); return a;
}

// ---------------- K0: pack X (concat) + pad Wi -----------------------------
__global__ __launch_bounds__(256) void k_pack(
  const float* __restrict__ inputs, const float* __restrict__ rvp,
  const float* __restrict__ hp, const float* __restrict__ Wi,
  float* __restrict__ X, float* __restrict__ Wip)
{
  const int blk = blockIdx.x, t = threadIdx.x;
  if (blk < Bsz){
    if (t < 160){
      const int c4 = t*4;
      float4 v;
      if (c4 < INsz)      v = *reinterpret_cast<const float4*>(inputs + (size_t)blk*INsz + c4);
      else if (c4 < XDIM) v = *reinterpret_cast<const float4*>(rvp + (size_t)blk*(Ww*Rr) + (c4-INsz));
      else                v = *reinterpret_cast<const float4*>(hp + (size_t)blk*Uu + (c4-XDIM));
      *reinterpret_cast<float4*>(X + (size_t)blk*KL + c4) = v;
    }
  } else {
    const int k = blk - Bsz;
    const int j2 = t + 256;
    float v0 = Wi[(size_t)k*IFACEsz + t];
    float v1 = (j2 < IFACEsz) ? Wi[(size_t)k*IFACEsz + j2] : 0.0f;
    Wip[(size_t)k*512 + t]  = v0;
    Wip[(size_t)k*512 + j2] = v1;
  }
}

// ---------------- K1: LSTM GEMM + epilogue fused ---------------------------
// grid (32 batch-tiles, 8 col-groups of 32 units), 512 threads.
// Thread owns (batch tb, gate tg, col-quad tx) -> 1 float4 accumulator.
__global__ __launch_bounds__(512) void k_lstm(
  const float* __restrict__ X, const float* __restrict__ Wk,
  const float* __restrict__ Wr, const float* __restrict__ bl,
  const float* __restrict__ cprev, float* __restrict__ h_out)
{
  const int t = threadIdx.x;
  const int tx = t & 7;          // col-quad within the 32-col group
  const int tg = (t >> 3) & 3;   // gate
  const int tb = t >> 5;         // batch 0..15
  const int b0 = blockIdx.x * 16;
  const int cg = blockIdx.y * 32;        // unit index base
  const int col = tg*256 + cg + tx*4;    // column in 1024
  __shared__ float Xs[16][68];
  __shared__ float zs[16][4][36];
  float4 acc = {0,0,0,0};
  for (int kc = 0; kc < KL; kc += 64){
    if (t < 256){
      int rr = t >> 4, cc = (t & 15)*4;
      *reinterpret_cast<float4*>(&Xs[rr][cc]) =
        *reinterpret_cast<const float4*>(X + (size_t)(b0+rr)*KL + kc + cc);
    }
    __syncthreads();
    const float* Wp = ((kc < XDIM) ? (Wk + (size_t)kc*G4) : (Wr + (size_t)(kc-XDIM)*G4)) + col;
    #pragma unroll 8
    for (int kk=0; kk<64; ++kk){
      float4 w4 = *reinterpret_cast<const float4*>(Wp + (size_t)kk*G4);
      acc = f4fma(Xs[tb][kk], w4, acc);
    }
    __syncthreads();
  }
  // add bias now
  {
    float4 b4 = *reinterpret_cast<const float4*>(bl + col);
    acc = f4add(acc, b4);
  }
  *reinterpret_cast<float4*>(&zs[tb][tg][tx*4]) = acc;
  __syncthreads();
  {
    const int b = t >> 5, c = t & 31;
    float zi = zs[b][0][c], zf = zs[b][1][c], zc_ = zs[b][2][c], zo = zs[b][3][c];
    float cc = sigf(zf)*cprev[(size_t)(b0+b)*Uu + cg + c] + sigf(zi)*tanhf(zc_);
    float h = sigf(zo)*tanhf(cc);
    h = fminf(fmaxf(h,-20.0f),20.0f);
    h_out[(size_t)(b0+b)*Uu + cg + c] = h;
  }
}

// ---------------- K2a: interface GEMM v = h * Wip --------------------------
__global__ __launch_bounds__(256) void k_ifgemm(
  const float* __restrict__ h_ws, const float* __restrict__ Wip, float* __restrict__ v_ws)
{
  const int t = threadIdx.x;
  const int tx = t & 15, ty = t >> 4;
  const int b0 = blockIdx.x*16;
  const int col = blockIdx.y*64 + tx*4;
  __shared__ float Hs[16][68];
  float4 acc = {0,0,0,0};
  for (int kc = 0; kc < Uu; kc += 64){
    {
      int rr = t >> 4, cc = (t & 15)*4;
      *reinterpret_cast<float4*>(&Hs[rr][cc]) =
        *reinterpret_cast<const float4*>(h_ws + (size_t)(b0+rr)*Uu + kc + cc);
    }
    __syncthreads();
    const float* Wp = Wip + (size_t)kc*512 + col;
    #pragma unroll 8
    for (int kk=0; kk<64; ++kk){
      float4 w4 = *reinterpret_cast<const float4*>(Wp + (size_t)kk*512);
      acc = f4fma(Hs[ty][kk], w4, acc);
    }
    __syncthreads();
  }
  *reinterpret_cast<float4*>(v_ws + (size_t)(b0+ty)*512 + col) = acc;
}

// ---------------- K2b: interface logic -------------------------------------
__global__ __launch_bounds__(256) void k_iface2(
  const float* __restrict__ v_ws, const float* __restrict__ bi,
  const float* __restrict__ usage, const float* __restrict__ wwp,
  const float* __restrict__ wrp, const float* __restrict__ prec,
  const float* __restrict__ M,
  float* __restrict__ ww_ws, float* __restrict__ er_ws, float* __restrict__ wv_ws,
  float* __restrict__ rk_ws, float* __restrict__ krn_ws, float* __restrict__ rstr_ws,
  float* __restrict__ rm_ws, float* __restrict__ P_ws, float* __restrict__ Q_ws)
{
  const int b = blockIdx.x, t = threadIdx.x;
  __shared__ float vl[IFACEsz];
  __shared__ float wkey[Ww];
  __shared__ float ul[Nn], sul[Nn], cpl[Nn], red[Nn];
  __shared__ float4 red4[Nn];
  __shared__ float scal[8];
  for (int j=t; j<IFACEsz; j+=256) vl[j] = v_ws[(size_t)b*512 + j] + bi[j];
  __syncthreads();
  if (t < Ww){
    wkey[t] = vl[260+t];
    er_ws[b*Ww+t] = sigf(vl[325+t]);
    wv_ws[b*Ww+t] = vl[389+t];
  }
  rk_ws[b*Ww*Rr + t] = vl[t];
  if (t < Rr){
    rstr_ws[b*Rr+t] = 1.0f + softplusf_(vl[256+t]);
    float ssum = 0.0f;
    for (int w=0;w<Ww;++w){ float v = vl[w*Rr+t]; ssum += v*v; }
    krn_ws[b*Rr+t] = sqrtf(ssum);
    float q0=vl[459+t], q1=vl[463+t], q2=vl[467+t];
    float mm = fmaxf(q0, fmaxf(q1,q2));
    float e0=expf(q0-mm), e1=expf(q1-mm), e2=expf(q2-mm);
    float inv = 1.0f/(e0+e1+e2);
    rm_ws[b*12 + t]     = e0*inv;
    rm_ws[b*12 + 4 + t] = e1*inv;
    rm_ws[b*12 + 8 + t] = e2*inv;
    scal[4+t] = sigf(vl[453+t]);
  }
  if (t == 0){
    scal[0] = 1.0f + softplusf_(vl[324]);
    scal[1] = sigf(vl[457]);
    scal[2] = sigf(vl[458]);
    float ssum=0.0f;
    for (int w=0;w<Ww;++w){ float v=vl[260+w]; ssum += v*v; }
    scal[3] = sqrtf(ssum);
  }
  __syncthreads();
  float4 wr4 = *reinterpret_cast<const float4*>(wrp + ((size_t)b*Nn + t)*Rr);
  float psi = (1.0f - scal[4]*wr4.x)*(1.0f - scal[5]*wr4.y)
            * (1.0f - scal[6]*wr4.z)*(1.0f - scal[7]*wr4.w);
  float us = usage[b*Nn+t], wp = wwp[b*Nn+t];
  float u = (us + wp - us*wp)*psi;
  ul[t] = u;
  __syncthreads();
  int rank = 0;
  for (int m=0;m<Nn;++m){
    float um = ul[m];
    rank += (um < u || (um == u && m < t)) ? 1 : 0;
  }
  sul[rank] = u;
  __syncthreads();
  cpl[t] = sul[t];
  __syncthreads();
  for (int d=1; d<Nn; d<<=1){
    float a = cpl[t];
    float m_ = (t >= d) ? cpl[t-d] : 1.0f;
    __syncthreads();
    cpl[t] = a*m_;
    __syncthreads();
  }
  float cpexcl = (rank == 0) ? 1.0f : cpl[rank-1];
  float alloc = (1.0f - u)*cpexcl;
  const float* Mrow = M + ((size_t)b*Nn + t)*Ww;
  float dot=0.0f, nrm=0.0f;
  #pragma unroll 4
  for (int w=0;w<Ww;w+=4){
    float4 m4 = *reinterpret_cast<const float4*>(Mrow + w);
    dot += m4.x*wkey[w] + m4.y*wkey[w+1] + m4.z*wkey[w+2] + m4.w*wkey[w+3];
    nrm += m4.x*m4.x + m4.y*m4.y + m4.z*m4.z + m4.w*m4.w;
  }
  float sim = dot/(sqrtf(nrm)*scal[3] + 1e-6f);
  float sc = scal[0]*sim;
  red[t] = sc; __syncthreads();
  for (int st=128; st>0; st>>=1){ if (t<st) red[t] = fmaxf(red[t], red[t+st]); __syncthreads(); }
  float mx = red[0]; __syncthreads();
  float e = expf(sc - mx);
  red[t] = e; __syncthreads();
  for (int st=128; st>0; st>>=1){ if (t<st) red[t] += red[t+st]; __syncthreads(); }
  float cw = e/red[0];
  float ww = scal[2]*(scal[1]*alloc + (1.0f - scal[1])*cw);
  ww_ws[b*Nn+t] = ww;
  __syncthreads();
  // P/Q via float4 trees
  float pr = prec[b*Nn+t];
  float4 pv; pv.x = pr*wr4.x; pv.y = pr*wr4.y; pv.z = pr*wr4.z; pv.w = pr*wr4.w;
  red4[t] = pv; __syncthreads();
  for (int st=128; st>0; st>>=1){ if (t<st) red4[t] = f4add(red4[t], red4[t+st]); __syncthreads(); }
  if (t==0) *reinterpret_cast<float4*>(P_ws + b*Rr) = red4[0];
  __syncthreads();
  float4 qv; qv.x = ww*wr4.x; qv.y = ww*wr4.y; qv.z = ww*wr4.z; qv.w = ww*wr4.w;
  red4[t] = qv; __syncthreads();
  for (int st=128; st>0; st>>=1){ if (t<st) red4[t] = f4add(red4[t], red4[t+st]); __syncthreads(); }
  if (t==0) *reinterpret_cast<float4*>(Q_ws + b*Rr) = red4[0];
}

// ---------------- K3: link products, strip-parallel ------------------------
// grid (B, 4): block handles 64 cols (col products over all rows, 4 row-groups)
// and 64 rows (row products, 16-lane groups). 256 threads.
__global__ __launch_bounds__(256) void k_link(
  const float* __restrict__ link, const float* __restrict__ wrp,
  const float* __restrict__ ww_ws,
  float* __restrict__ rowA, float* __restrict__ rowC,
  float* __restrict__ colA, float* __restrict__ colC, float* __restrict__ diag)
{
  const int b = blockIdx.x, s = blockIdx.y, t = threadIdx.x;
  __shared__ float4 wrl4[Nn];          // AoS for broadcast
  __shared__ float wrs[4][Nn];         // SoA for row pass
  __shared__ float wws[Nn];
  __shared__ float4 credA[4][64], credC[4][64];
  {
    float4 w4 = *reinterpret_cast<const float4*>(wrp + ((size_t)b*Nn + t)*Rr);
    wrl4[t] = w4;
    wrs[0][t] = w4.x; wrs[1][t] = w4.y; wrs[2][t] = w4.z; wrs[3][t] = w4.w;
    wws[t] = ww_ws[(size_t)b*Nn + t];
  }
  __syncthreads();
  const float* Lb = link + (size_t)b*Nn*Nn;
  // ---- col pass: col = s*64 + (t&63); group g covers rows g*64..g*64+63
  {
    const int c = t & 63, g = t >> 6;
    const int cidx = s*64 + c;
    float4 cA = {0,0,0,0}, cC = {0,0,0,0};
    const float* Lp = Lb + (size_t)(g*64)*Nn + cidx;
    #pragma unroll 4
    for (int i=0;i<64;++i){
      const int n = g*64 + i;
      float l = Lp[(size_t)i*Nn];
      float4 wn = wrl4[n];
      cA = f4fma(l, wn, cA);
      cC = f4fma(l*wws[n], wn, cC);
      if (n == cidx) diag[(size_t)b*Nn + cidx] = l;
    }
    credA[g][c] = cA; credC[g][c] = cC;
  }
  __syncthreads();
  if (t < 64){
    float4 sA = f4add(f4add(credA[0][t], credA[1][t]), f4add(credA[2][t], credA[3][t]));
    *reinterpret_cast<float4*>(colA + ((size_t)b*Nn + s*64 + t)*Rr) = sA;
  } else if (t < 128){
    const int c = t - 64;
    float4 sC = f4add(f4add(credC[0][c], credC[1][c]), f4add(credC[2][c], credC[3][c]));
    *reinterpret_cast<float4*>(colC + ((size_t)b*Nn + s*64 + c)*Rr) = sC;
  }
  // ---- row pass: rows s*64 .. s*64+63; 16 lanes per row
  const int wave = t >> 6, lane = t & 63;
  const int rg = lane >> 4, li = lane & 15;
  #pragma unroll
  for (int it=0; it<4; ++it){
    const int n = s*64 + wave*16 + it*4 + rg;
    const float* Lr = Lb + (size_t)n*Nn;
    float ra0=0,ra1=0,ra2=0,ra3=0, rc0=0,rc1=0,rc2=0,rc3=0;
    #pragma unroll
    for (int ch=0; ch<4; ++ch){
      const int m0 = ch*64 + li*4;
      float4 l4 = *reinterpret_cast<const float4*>(Lr + m0);
      float4 wwm = *reinterpret_cast<const float4*>(&wws[m0]);
      float4 lw; lw.x=l4.x*wwm.x; lw.y=l4.y*wwm.y; lw.z=l4.z*wwm.z; lw.w=l4.w*wwm.w;
      float4 w0 = *reinterpret_cast<const float4*>(&wrs[0][m0]);
      float4 w1 = *reinterpret_cast<const float4*>(&wrs[1][m0]);
      float4 w2 = *reinterpret_cast<const float4*>(&wrs[2][m0]);
      float4 w3 = *reinterpret_cast<const float4*>(&wrs[3][m0]);
      ra0 += l4.x*w0.x + l4.y*w0.y + l4.z*w0.z + l4.w*w0.w;
      ra1 += l4.x*w1.x + l4.y*w1.y + l4.z*w1.z + l4.w*w1.w;
      ra2 += l4.x*w2.x + l4.y*w2.y + l4.z*w2.z + l4.w*w2.w;
      ra3 += l4.x*w3.x + l4.y*w3.y + l4.z*w3.z + l4.w*w3.w;
      rc0 += lw.x*w0.x + lw.y*w0.y + lw.z*w0.z + lw.w*w0.w;
      rc1 += lw.x*w1.x + lw.y*w1.y + lw.z*w1.z + lw.w*w1.w;
      rc2 += lw.x*w2.x + lw.y*w2.y + lw.z*w2.z + lw.w*w2.w;
      rc3 += lw.x*w3.x + lw.y*w3.y + lw.z*w3.z + lw.w*w3.w;
    }
    #pragma unroll
    for (int off=8; off>=1; off>>=1){
      ra0 += __shfl_down(ra0, off, 16); ra1 += __shfl_down(ra1, off, 16);
      ra2 += __shfl_down(ra2, off, 16); ra3 += __shfl_down(ra3, off, 16);
      rc0 += __shfl_down(rc0, off, 16); rc1 += __shfl_down(rc1, off, 16);
      rc2 += __shfl_down(rc2, off, 16); rc3 += __shfl_down(rc3, off, 16);
    }
    if (li == 0){
      float4 oA; oA.x=ra0; oA.y=ra1; oA.z=ra2; oA.w=ra3;
      float4 oC; oC.x=rc0; oC.y=rc1; oC.z=rc2; oC.w=rc3;
      *reinterpret_cast<float4*>(rowA + ((size_t)b*Nn + n)*Rr) = oA;
      *reinterpret_cast<float4*>(rowC + ((size_t)b*Nn + n)*Rr) = oC;
    }
  }
}

// ---------------- K4: fwd/bwd + read addressing + wr + read vectors --------
__global__ __launch_bounds__(256) void k_readw_rv(
  const float* __restrict__ M, const float* __restrict__ ww_ws,
  const float* __restrict__ er_ws, const float* __restrict__ wv_ws,
  const float* __restrict__ rk_ws, const float* __restrict__ krn_ws,
  const float* __restrict__ rstr_ws, const float* __restrict__ rm_ws,
  const float* __restrict__ P_ws, const float* __restrict__ Q_ws,
  const float* __restrict__ rowA, const float* __restrict__ rowC,
  const float* __restrict__ colA, const float* __restrict__ colC,
  const float* __restrict__ diag, const float* __restrict__ wrp,
  const float* __restrict__ prec, float* __restrict__ rv_ws)
{
  const int b = blockIdx.x, t = threadIdx.x;
  __shared__ float rkl[Ww*Rr];
  __shared__ float erl[Ww], wvl[Ww];
  __shared__ float4 red4[Nn];
  __shared__ float wrl[Nn][4];
  __shared__ float wwl[Nn];
  rkl[t] = rk_ws[b*Ww*Rr + t];
  if (t < Ww){ erl[t] = er_ws[b*Ww+t]; wvl[t] = wv_ws[b*Ww+t]; }
  const float ww = ww_ws[b*Nn+t];
  wwl[t] = ww;
  __syncthreads();
  const float pr = prec[b*Nn+t];
  const float dg = diag[b*Nn+t];
  float4 wr4 = *reinterpret_cast<const float4*>(wrp + ((size_t)b*Nn+t)*Rr);
  const float Lnn = (1.0f - 2.0f*ww)*dg + ww*pr;
  float4 rA = *reinterpret_cast<const float4*>(rowA + ((size_t)b*Nn+t)*Rr);
  float4 rC = *reinterpret_cast<const float4*>(rowC + ((size_t)b*Nn+t)*Rr);
  float4 cA = *reinterpret_cast<const float4*>(colA + ((size_t)b*Nn+t)*Rr);
  float4 cC = *reinterpret_cast<const float4*>(colC + ((size_t)b*Nn+t)*Rr);
  float4 Pv = *reinterpret_cast<const float4*>(P_ws + b*Rr);
  float4 Qv = *reinterpret_cast<const float4*>(Q_ws + b*Rr);
  float fwdv[4], bwdv[4];
  fwdv[0] = (1.0f-ww)*rA.x - rC.x + ww*Pv.x - Lnn*wr4.x;
  fwdv[1] = (1.0f-ww)*rA.y - rC.y + ww*Pv.y - Lnn*wr4.y;
  fwdv[2] = (1.0f-ww)*rA.z - rC.z + ww*Pv.z - Lnn*wr4.z;
  fwdv[3] = (1.0f-ww)*rA.w - rC.w + ww*Pv.w - Lnn*wr4.w;
  bwdv[0] = (1.0f-ww)*cA.x - cC.x + pr*Qv.x - Lnn*wr4.x;
  bwdv[1] = (1.0f-ww)*cA.y - cC.y + pr*Qv.y - Lnn*wr4.y;
  bwdv[2] = (1.0f-ww)*cA.z - cC.z + pr*Qv.z - Lnn*wr4.z;
  bwdv[3] = (1.0f-ww)*cA.w - cC.w + pr*Qv.w - Lnn*wr4.w;
  const float* Mrow = M + ((size_t)b*Nn + t)*Ww;
  float s0=0,s1=0,s2=0,s3=0, nrm=0;
  #pragma unroll 4
  for (int w=0;w<Ww;w+=4){
    float4 m4 = *reinterpret_cast<const float4*>(Mrow + w);
    float mvs[4] = {m4.x, m4.y, m4.z, m4.w};
    #pragma unroll
    for (int i=0;i<4;++i){
      int w_ = w+i;
      float mn = mvs[i]*(1.0f - ww*erl[w_]) + ww*wvl[w_];
      nrm += mn*mn;
      float4 k4 = *reinterpret_cast<const float4*>(&rkl[w_*4]);
      s0 += mn*k4.x; s1 += mn*k4.y; s2 += mn*k4.z; s3 += mn*k4.w;
    }
  }
  float mnorm = sqrtf(nrm);
  float4 kn = *reinterpret_cast<const float4*>(krn_ws + b*Rr);
  float4 rs = *reinterpret_cast<const float4*>(rstr_ws + b*Rr);
  float4 aa4;
  aa4.x = rs.x*(s0/(mnorm*kn.x + 1e-6f));
  aa4.y = rs.y*(s1/(mnorm*kn.y + 1e-6f));
  aa4.z = rs.z*(s2/(mnorm*kn.z + 1e-6f));
  aa4.w = rs.w*(s3/(mnorm*kn.w + 1e-6f));
  // vectorized softmax over n (column dim) for all 4 read heads at once
  red4[t] = aa4; __syncthreads();
  for (int st=128; st>0; st>>=1){ if (t<st) red4[t] = f4max(red4[t], red4[t+st]); __syncthreads(); }
  float4 mx4 = red4[0]; __syncthreads();
  float4 e4;
  e4.x = expf(aa4.x - mx4.x); e4.y = expf(aa4.y - mx4.y);
  e4.z = expf(aa4.z - mx4.z); e4.w = expf(aa4.w - mx4.w);
  red4[t] = e4; __syncthreads();
  for (int st=128; st>0; st>>=1){ if (t<st) red4[t] = f4add(red4[t], red4[t+st]); __syncthreads(); }
  float4 sm4 = red4[0];
  float cr[4] = {e4.x/sm4.x, e4.y/sm4.y, e4.z/sm4.z, e4.w/sm4.w};
  float wro[4];
  #pragma unroll
  for (int r=0;r<4;++r){
    float m0 = rm_ws[b*12 + r];
    float m1 = rm_ws[b*12 + 4 + r];
    float m2 = rm_ws[b*12 + 8 + r];
    wro[r] = m0*bwdv[r] + m1*cr[r] + m2*fwdv[r];
  }
  wrl[t][0]=wro[0]; wrl[t][1]=wro[1]; wrl[t][2]=wro[2]; wrl[t][3]=wro[3];
  __syncthreads();
  // read vectors: thread = (w, r)
  {
    const int w = t & 63, r = t >> 6;
    const float er_w = erl[w], wv_w = wvl[w];
    float acc = 0.0f;
    #pragma unroll 4
    for (int n=0;n<Nn;++n){
      float m = M[((size_t)b*Nn + n)*Ww + w];
      float wwn = wwl[n];
      float mn = m*(1.0f - wwn*er_w) + wwn*wv_w;
      acc += mn*wrl[n][r];
    }
    rv_ws[(size_t)b*(Ww*Rr) + w*Rr + r] = acc;
  }
}

// ---------------- K5: output GEMM ------------------------------------------
__global__ __launch_bounds__(256) void k_final(
  const float* __restrict__ h_ws, const float* __restrict__ rv_ws,
  const float* __restrict__ Wo, const float* __restrict__ bo,
  float* __restrict__ out)
{
  const int t = threadIdx.x;
  const int tx = t & 15, ty = t >> 4;
  const int b0 = blockIdx.x*16;
  const int col = blockIdx.y*64 + tx*4;
  __shared__ float Cs[16][68];
  float4 acc = {0,0,0,0};
  for (int kc = 0; kc < 512; kc += 64){
    {
      int rr = t >> 4, cc = (t & 15)*4;
      const float* src = (kc < Uu)
        ? (h_ws  + (size_t)(b0+rr)*Uu + kc + cc)
        : (rv_ws + (size_t)(b0+rr)*(Ww*Rr) + (kc-Uu) + cc);
      *reinterpret_cast<float4*>(&Cs[rr][cc]) = *reinterpret_cast<const float4*>(src);
    }
    __syncthreads();
    const float* Wp = Wo + (size_t)kc*OUTsz + col;
    #pragma unroll 8
    for (int kk=0; kk<64; ++kk){
      float4 w4 = *reinterpret_cast<const float4*>(Wp + (size_t)kk*OUTsz);
      acc = f4fma(Cs[ty][kk], w4, acc);
    }
    __syncthreads();
  }
  float4 b4 = *reinterpret_cast<const float4*>(bo + col);
  acc.x = fminf(fmaxf(acc.x + b4.x, -20.0f), 20.0f);
  acc.y = fminf(fmaxf(acc.y + b4.y, -20.0f), 20.0f);
  acc.z = fminf(fmaxf(acc.z + b4.z, -20.0f), 20.0f);
  acc.w = fminf(fmaxf(acc.w + b4.w, -20.0f), 20.0f);
  *reinterpret_cast<float4*>(out + (size_t)(b0+ty)*OUTsz + col) = acc;
}

extern "C" void kernel_launch(void* const* d_in, const int* in_sizes, int n_in,
                              void* d_out, int out_size, void* d_ws, size_t ws_size,
                              hipStream_t stream)
{
  const float* inputs = (const float*)d_in[0];
  const float* M      = (const float*)d_in[1];
  const float* usage  = (const float*)d_in[2];
  const float* link   = (const float*)d_in[3];
  const float* prec   = (const float*)d_in[4];
  const float* wwp    = (const float*)d_in[5];
  const float* wrp    = (const float*)d_in[6];
  const float* hp     = (const float*)d_in[7];
  const float* cp     = (const float*)d_in[8];
  const float* rvp    = (const float*)d_in[9];
  const float* Wk     = (const float*)d_in[10];
  const float* Wr     = (const float*)d_in[11];
  const float* bl     = (const float*)d_in[12];
  const float* Wi     = (const float*)d_in[13];
  const float* bi     = (const float*)d_in[14];
  const float* Wo     = (const float*)d_in[15];
  const float* bo     = (const float*)d_in[16];

  float* ws = (float*)d_ws;
  float* X_ws    = ws;                                  // 512*640
  float* Wip     = X_ws   + (size_t)Bsz*KL;             // 256*512
  float* v_ws    = Wip    + (size_t)Uu*512;             // 512*512
  float* h_ws    = v_ws   + (size_t)Bsz*512;            // 512*256
  float* ww_ws   = h_ws   + (size_t)Bsz*Uu;
  float* er_ws   = ww_ws  + (size_t)Bsz*Nn;
  float* wv_ws   = er_ws  + (size_t)Bsz*Ww;
  float* rk_ws   = wv_ws  + (size_t)Bsz*Ww;
  float* krn_ws  = rk_ws  + (size_t)Bsz*Ww*Rr;
  float* rstr_ws = krn_ws + (size_t)Bsz*Rr;
  float* rm_ws   = rstr_ws+ (size_t)Bsz*Rr;
  float* P_ws    = rm_ws  + (size_t)Bsz*3*Rr;
  float* Q_ws    = P_ws   + (size_t)Bsz*Rr;
  float* rowA    = Q_ws   + (size_t)Bsz*Rr;
  float* rowC    = rowA   + (size_t)Bsz*Nn*Rr;
  float* colA    = rowC   + (size_t)Bsz*Nn*Rr;
  float* colC    = colA   + (size_t)Bsz*Nn*Rr;
  float* diag    = colC   + (size_t)Bsz*Nn*Rr;
  float* rv_ws   = diag   + (size_t)Bsz*Nn;

  k_pack<<<dim3(Bsz + Uu), dim3(256), 0, stream>>>(inputs, rvp, hp, Wi, X_ws, Wip);
  k_lstm<<<dim3(32,8), dim3(512), 0, stream>>>(X_ws, Wk, Wr, bl, cp, h_ws);
  k_ifgemm<<<dim3(32,8), dim3(256), 0, stream>>>(h_ws, Wip, v_ws);
  k_iface2<<<dim3(Bsz), dim3(256), 0, stream>>>(v_ws, bi, usage, wwp, wrp, prec, M,
      ww_ws, er_ws, wv_ws, rk_ws, krn_ws, rstr_ws, rm_ws, P_ws, Q_ws);
  k_link<<<dim3(Bsz,4), dim3(256), 0, stream>>>(link, wrp, ww_ws, rowA, rowC, colA, colC, diag);
  k_readw_rv<<<dim3(Bsz), dim3(256), 0, stream>>>(M, ww_ws, er_ws, wv_ws, rk_ws, krn_ws,
      rstr_ws, rm_ws, P_ws, Q_ws, rowA, rowC, colA, colC, diag, wrp, prec, rv_ws);
  k_final<<<dim3(32,2), dim3(256), 0, stream>>>(h_ws, rv_ws, Wo, bo, (float*)d_out);
}

// Round 4
// 224.706 us; speedup vs baseline: 1.1624x; 1.1308x over previous
//
#include <hip/hip_runtime.h>
#include <math.h>

#define Bsz 512
#define INsz 128
#define Nn 256
#define Ww 64
#define Rr 4
#define Uu 256
#define OUTsz 128
#define IFACEsz 471
#define XDIM 384   /* IN + W*R */
#define KL 640     /* XDIM + U */
#define G4 1024    /* 4*U */

__device__ __forceinline__ float sigf(float x){ return 1.0f/(1.0f+expf(-x)); }
__device__ __forceinline__ float softplusf_(float x){ return fmaxf(x,0.0f) + log1pf(expf(-fabsf(x))); }
__device__ __forceinline__ float4 f4fma(float s, float4 a, float4 acc){
  acc.x += s*a.x; acc.y += s*a.y; acc.z += s*a.z; acc.w += s*a.w; return acc;
}
__device__ __forceinline__ float4 f4add(float4 a, float4 b){
  a.x+=b.x; a.y+=b.y; a.z+=b.z; a.w+=b.w; return a;
}
__device__ __forceinline__ float4 f4max(float4 a, float4 b){
  a.x=fmaxf(a.x,b.x); a.y=fmaxf(a.y,b.y); a.z=fmaxf(a.z,b.z); a.w=fmaxf(a.w,b.w); return a;
}

// ---------------- K0: pack X (concat) + pad Wi -----------------------------
__global__ __launch_bounds__(256) void k_pack(
  const float* __restrict__ inputs, const float* __restrict__ rvp,
  const float* __restrict__ hp, const float* __restrict__ Wi,
  float* __restrict__ X, float* __restrict__ Wip)
{
  const int blk = blockIdx.x, t = threadIdx.x;
  if (blk < Bsz){
    if (t < 160){
      const int c4 = t*4;
      float4 v;
      if (c4 < INsz)      v = *reinterpret_cast<const float4*>(inputs + (size_t)blk*INsz + c4);
      else if (c4 < XDIM) v = *reinterpret_cast<const float4*>(rvp + (size_t)blk*(Ww*Rr) + (c4-INsz));
      else                v = *reinterpret_cast<const float4*>(hp + (size_t)blk*Uu + (c4-XDIM));
      *reinterpret_cast<float4*>(X + (size_t)blk*KL + c4) = v;
    }
  } else {
    const int k = blk - Bsz;
    const int j2 = t + 256;
    float v0 = Wi[(size_t)k*IFACEsz + t];
    float v1 = (j2 < IFACEsz) ? Wi[(size_t)k*IFACEsz + j2] : 0.0f;
    Wip[(size_t)k*512 + t]  = v0;
    Wip[(size_t)k*512 + j2] = v1;
  }
}

// ---------------- K1: LSTM GEMM + epilogue fused ---------------------------
__global__ __launch_bounds__(512) void k_lstm(
  const float* __restrict__ X, const float* __restrict__ Wk,
  const float* __restrict__ Wr, const float* __restrict__ bl,
  const float* __restrict__ cprev, float* __restrict__ h_out)
{
  const int t = threadIdx.x;
  const int tx = t & 7;          // col-quad within the 32-col group
  const int tg = (t >> 3) & 3;   // gate
  const int tb = t >> 5;         // batch 0..15
  const int b0 = blockIdx.x * 16;
  const int cg = blockIdx.y * 32;        // unit index base
  const int col = tg*256 + cg + tx*4;    // column in 1024
  __shared__ float Xs[16][68];
  __shared__ float zs[16][4][36];
  float4 acc = {0,0,0,0};
  for (int kc = 0; kc < KL; kc += 64){
    if (t < 256){
      int rr = t >> 4, cc = (t & 15)*4;
      *reinterpret_cast<float4*>(&Xs[rr][cc]) =
        *reinterpret_cast<const float4*>(X + (size_t)(b0+rr)*KL + kc + cc);
    }
    __syncthreads();
    const float* Wp = ((kc < XDIM) ? (Wk + (size_t)kc*G4) : (Wr + (size_t)(kc-XDIM)*G4)) + col;
    #pragma unroll 8
    for (int kk=0; kk<64; ++kk){
      float4 w4 = *reinterpret_cast<const float4*>(Wp + (size_t)kk*G4);
      acc = f4fma(Xs[tb][kk], w4, acc);
    }
    __syncthreads();
  }
  {
    float4 b4 = *reinterpret_cast<const float4*>(bl + col);
    acc = f4add(acc, b4);
  }
  *reinterpret_cast<float4*>(&zs[tb][tg][tx*4]) = acc;
  __syncthreads();
  {
    const int b = t >> 5, c = t & 31;
    float zi = zs[b][0][c], zf = zs[b][1][c], zc_ = zs[b][2][c], zo = zs[b][3][c];
    float cc = sigf(zf)*cprev[(size_t)(b0+b)*Uu + cg + c] + sigf(zi)*tanhf(zc_);
    float h = sigf(zo)*tanhf(cc);
    h = fminf(fmaxf(h,-20.0f),20.0f);
    h_out[(size_t)(b0+b)*Uu + cg + c] = h;
  }
}

// ---------------- K2a: interface GEMM v = h * Wip --------------------------
__global__ __launch_bounds__(256) void k_ifgemm(
  const float* __restrict__ h_ws, const float* __restrict__ Wip, float* __restrict__ v_ws)
{
  const int t = threadIdx.x;
  const int tx = t & 15, ty = t >> 4;
  const int b0 = blockIdx.x*16;
  const int col = blockIdx.y*64 + tx*4;
  __shared__ float Hs[16][68];
  float4 acc = {0,0,0,0};
  for (int kc = 0; kc < Uu; kc += 64){
    {
      int rr = t >> 4, cc = (t & 15)*4;
      *reinterpret_cast<float4*>(&Hs[rr][cc]) =
        *reinterpret_cast<const float4*>(h_ws + (size_t)(b0+rr)*Uu + kc + cc);
    }
    __syncthreads();
    const float* Wp = Wip + (size_t)kc*512 + col;
    #pragma unroll 8
    for (int kk=0; kk<64; ++kk){
      float4 w4 = *reinterpret_cast<const float4*>(Wp + (size_t)kk*512);
      acc = f4fma(Hs[ty][kk], w4, acc);
    }
    __syncthreads();
  }
  *reinterpret_cast<float4*>(v_ws + (size_t)(b0+ty)*512 + col) = acc;
}

// ---------------- K2b: interface logic -------------------------------------
__global__ __launch_bounds__(256) void k_iface2(
  const float* __restrict__ v_ws, const float* __restrict__ bi,
  const float* __restrict__ usage, const float* __restrict__ wwp,
  const float* __restrict__ wrp, const float* __restrict__ prec,
  const float* __restrict__ M,
  float* __restrict__ ww_ws, float* __restrict__ er_ws, float* __restrict__ wv_ws,
  float* __restrict__ rk_ws, float* __restrict__ krn_ws, float* __restrict__ rstr_ws,
  float* __restrict__ rm_ws, float* __restrict__ P_ws, float* __restrict__ Q_ws)
{
  const int b = blockIdx.x, t = threadIdx.x;
  __shared__ float vl[IFACEsz];
  __shared__ float wkey[Ww];
  __shared__ float ul[Nn], sul[Nn], cpl[Nn], red[Nn];
  __shared__ float4 red4[Nn];
  __shared__ float scal[8];
  for (int j=t; j<IFACEsz; j+=256) vl[j] = v_ws[(size_t)b*512 + j] + bi[j];
  __syncthreads();
  if (t < Ww){
    wkey[t] = vl[260+t];
    er_ws[b*Ww+t] = sigf(vl[325+t]);
    wv_ws[b*Ww+t] = vl[389+t];
  }
  rk_ws[b*Ww*Rr + t] = vl[t];
  if (t < Rr){
    rstr_ws[b*Rr+t] = 1.0f + softplusf_(vl[256+t]);
    float ssum = 0.0f;
    for (int w=0;w<Ww;++w){ float v = vl[w*Rr+t]; ssum += v*v; }
    krn_ws[b*Rr+t] = sqrtf(ssum);
    float q0=vl[459+t], q1=vl[463+t], q2=vl[467+t];
    float mm = fmaxf(q0, fmaxf(q1,q2));
    float e0=expf(q0-mm), e1=expf(q1-mm), e2=expf(q2-mm);
    float inv = 1.0f/(e0+e1+e2);
    rm_ws[b*12 + t]     = e0*inv;
    rm_ws[b*12 + 4 + t] = e1*inv;
    rm_ws[b*12 + 8 + t] = e2*inv;
    scal[4+t] = sigf(vl[453+t]);
  }
  if (t == 0){
    scal[0] = 1.0f + softplusf_(vl[324]);
    scal[1] = sigf(vl[457]);
    scal[2] = sigf(vl[458]);
    float ssum=0.0f;
    for (int w=0;w<Ww;++w){ float v=vl[260+w]; ssum += v*v; }
    scal[3] = sqrtf(ssum);
  }
  __syncthreads();
  float4 wr4 = *reinterpret_cast<const float4*>(wrp + ((size_t)b*Nn + t)*Rr);
  float psi = (1.0f - scal[4]*wr4.x)*(1.0f - scal[5]*wr4.y)
            * (1.0f - scal[6]*wr4.z)*(1.0f - scal[7]*wr4.w);
  float us = usage[b*Nn+t], wp = wwp[b*Nn+t];
  float u = (us + wp - us*wp)*psi;
  ul[t] = u;
  __syncthreads();
  int rank = 0;
  for (int m=0;m<Nn;++m){
    float um = ul[m];
    rank += (um < u || (um == u && m < t)) ? 1 : 0;
  }
  sul[rank] = u;
  __syncthreads();
  cpl[t] = sul[t];
  __syncthreads();
  for (int d=1; d<Nn; d<<=1){
    float a = cpl[t];
    float m_ = (t >= d) ? cpl[t-d] : 1.0f;
    __syncthreads();
    cpl[t] = a*m_;
    __syncthreads();
  }
  float cpexcl = (rank == 0) ? 1.0f : cpl[rank-1];
  float alloc = (1.0f - u)*cpexcl;
  const float* Mrow = M + ((size_t)b*Nn + t)*Ww;
  float dot=0.0f, nrm=0.0f;
  #pragma unroll 4
  for (int w=0;w<Ww;w+=4){
    float4 m4 = *reinterpret_cast<const float4*>(Mrow + w);
    dot += m4.x*wkey[w] + m4.y*wkey[w+1] + m4.z*wkey[w+2] + m4.w*wkey[w+3];
    nrm += m4.x*m4.x + m4.y*m4.y + m4.z*m4.z + m4.w*m4.w;
  }
  float sim = dot/(sqrtf(nrm)*scal[3] + 1e-6f);
  float sc = scal[0]*sim;
  red[t] = sc; __syncthreads();
  for (int st=128; st>0; st>>=1){ if (t<st) red[t] = fmaxf(red[t], red[t+st]); __syncthreads(); }
  float mx = red[0]; __syncthreads();
  float e = expf(sc - mx);
  red[t] = e; __syncthreads();
  for (int st=128; st>0; st>>=1){ if (t<st) red[t] += red[t+st]; __syncthreads(); }
  float cw = e/red[0];
  float ww = scal[2]*(scal[1]*alloc + (1.0f - scal[1])*cw);
  ww_ws[b*Nn+t] = ww;
  __syncthreads();
  float pr = prec[b*Nn+t];
  float4 pv; pv.x = pr*wr4.x; pv.y = pr*wr4.y; pv.z = pr*wr4.z; pv.w = pr*wr4.w;
  red4[t] = pv; __syncthreads();
  for (int st=128; st>0; st>>=1){ if (t<st) red4[t] = f4add(red4[t], red4[t+st]); __syncthreads(); }
  if (t==0) *reinterpret_cast<float4*>(P_ws + b*Rr) = red4[0];
  __syncthreads();
  float4 qv; qv.x = ww*wr4.x; qv.y = ww*wr4.y; qv.z = ww*wr4.z; qv.w = ww*wr4.w;
  red4[t] = qv; __syncthreads();
  for (int st=128; st>0; st>>=1){ if (t<st) red4[t] = f4add(red4[t], red4[t+st]); __syncthreads(); }
  if (t==0) *reinterpret_cast<float4*>(Q_ws + b*Rr) = red4[0];
}

// ---------------- K3: link products via LDS tile ---------------------------
// grid (B, 4): block stages 64-row x 256-col tile of link in LDS (one read),
// then computes row products (4 threads/row, width-4 shfl) and col partials.
__global__ __launch_bounds__(256) void k_link(
  const float* __restrict__ link, const float* __restrict__ wrp,
  const float* __restrict__ ww_ws,
  float* __restrict__ rowA, float* __restrict__ rowC,
  float* __restrict__ colAp, float* __restrict__ colCp, float* __restrict__ diag)
{
  const int b = blockIdx.x, s = blockIdx.y, t = threadIdx.x;
  const int n0 = s*64;
  __shared__ float Ls[64][260];
  __shared__ float4 wrl4[Nn];
  __shared__ float wws[Nn];
  wrl4[t] = *reinterpret_cast<const float4*>(wrp + ((size_t)b*Nn + t)*Rr);
  wws[t]  = ww_ws[(size_t)b*Nn + t];
  const float* Lb = link + (size_t)b*Nn*Nn;
  // stage tile: 16 independent float4 loads per thread (deep MLP, coalesced)
  #pragma unroll
  for (int k=0;k<16;++k){
    const int idx = k*256 + t;
    const int row = idx >> 6, c4 = (idx & 63)*4;
    float4 v = *reinterpret_cast<const float4*>(Lb + (size_t)(n0+row)*Nn + c4);
    *reinterpret_cast<float4*>(&Ls[row][c4]) = v;
  }
  __syncthreads();
  if (t < 64) diag[(size_t)b*Nn + n0 + t] = Ls[t][n0 + t];
  // ---- col pass: thread = column, accumulate over the 64 tile rows
  {
    float4 cA = {0,0,0,0}, cC = {0,0,0,0};
    #pragma unroll 8
    for (int i=0;i<64;++i){
      float l = Ls[i][t];
      const int n = n0 + i;
      float4 wn = wrl4[n];
      cA = f4fma(l, wn, cA);
      cC = f4fma(l*wws[n], wn, cC);
    }
    *reinterpret_cast<float4*>(colAp + (((size_t)s*Bsz + b)*Nn + t)*Rr) = cA;
    *reinterpret_cast<float4*>(colCp + (((size_t)s*Bsz + b)*Nn + t)*Rr) = cC;
  }
  // ---- row pass: 4 threads per row, each covers 64 contiguous cols
  {
    const int row = t >> 2, seg = t & 3;
    float ra0=0,ra1=0,ra2=0,ra3=0, rc0=0,rc1=0,rc2=0,rc3=0;
    #pragma unroll 4
    for (int k=0;k<16;++k){
      const int c4 = seg*64 + k*4;
      float4 l4 = *reinterpret_cast<float4*>(&Ls[row][c4]);
      float4 ww4 = *reinterpret_cast<float4*>(&wws[c4]);
      float4 w0 = wrl4[c4], w1 = wrl4[c4+1], w2 = wrl4[c4+2], w3 = wrl4[c4+3];
      ra0 += l4.x*w0.x + l4.y*w1.x + l4.z*w2.x + l4.w*w3.x;
      ra1 += l4.x*w0.y + l4.y*w1.y + l4.z*w2.y + l4.w*w3.y;
      ra2 += l4.x*w0.z + l4.y*w1.z + l4.z*w2.z + l4.w*w3.z;
      ra3 += l4.x*w0.w + l4.y*w1.w + l4.z*w2.w + l4.w*w3.w;
      float lx=l4.x*ww4.x, ly=l4.y*ww4.y, lz=l4.z*ww4.z, lw=l4.w*ww4.w;
      rc0 += lx*w0.x + ly*w1.x + lz*w2.x + lw*w3.x;
      rc1 += lx*w0.y + ly*w1.y + lz*w2.y + lw*w3.y;
      rc2 += lx*w0.z + ly*w1.z + lz*w2.z + lw*w3.z;
      rc3 += lx*w0.w + ly*w1.w + lz*w2.w + lw*w3.w;
    }
    #pragma unroll
    for (int off=2; off>=1; off>>=1){
      ra0 += __shfl_down(ra0, off, 4); ra1 += __shfl_down(ra1, off, 4);
      ra2 += __shfl_down(ra2, off, 4); ra3 += __shfl_down(ra3, off, 4);
      rc0 += __shfl_down(rc0, off, 4); rc1 += __shfl_down(rc1, off, 4);
      rc2 += __shfl_down(rc2, off, 4); rc3 += __shfl_down(rc3, off, 4);
    }
    if (seg == 0){
      float4 oA; oA.x=ra0; oA.y=ra1; oA.z=ra2; oA.w=ra3;
      float4 oC; oC.x=rc0; oC.y=rc1; oC.z=rc2; oC.w=rc3;
      *reinterpret_cast<float4*>(rowA + ((size_t)b*Nn + n0 + row)*Rr) = oA;
      *reinterpret_cast<float4*>(rowC + ((size_t)b*Nn + n0 + row)*Rr) = oC;
    }
  }
}

// ---------------- K4: fwd/bwd + read addressing + wr + read vectors --------
__global__ __launch_bounds__(256) void k_readw_rv(
  const float* __restrict__ M, const float* __restrict__ ww_ws,
  const float* __restrict__ er_ws, const float* __restrict__ wv_ws,
  const float* __restrict__ rk_ws, const float* __restrict__ krn_ws,
  const float* __restrict__ rstr_ws, const float* __restrict__ rm_ws,
  const float* __restrict__ P_ws, const float* __restrict__ Q_ws,
  const float* __restrict__ rowA, const float* __restrict__ rowC,
  const float* __restrict__ colAp, const float* __restrict__ colCp,
  const float* __restrict__ diag, const float* __restrict__ wrp,
  const float* __restrict__ prec, float* __restrict__ rv_ws)
{
  const int b = blockIdx.x, t = threadIdx.x;
  __shared__ float rkl[Ww*Rr];
  __shared__ float erl[Ww], wvl[Ww];
  __shared__ float4 red4[Nn];
  __shared__ float wrl[Nn][4];
  __shared__ float wwl[Nn];
  rkl[t] = rk_ws[b*Ww*Rr + t];
  if (t < Ww){ erl[t] = er_ws[b*Ww+t]; wvl[t] = wv_ws[b*Ww+t]; }
  const float ww = ww_ws[b*Nn+t];
  wwl[t] = ww;
  __syncthreads();
  const float pr = prec[b*Nn+t];
  const float dg = diag[b*Nn+t];
  float4 wr4 = *reinterpret_cast<const float4*>(wrp + ((size_t)b*Nn+t)*Rr);
  const float Lnn = (1.0f - 2.0f*ww)*dg + ww*pr;
  float4 rA = *reinterpret_cast<const float4*>(rowA + ((size_t)b*Nn+t)*Rr);
  float4 rC = *reinterpret_cast<const float4*>(rowC + ((size_t)b*Nn+t)*Rr);
  float4 cA = {0,0,0,0}, cC = {0,0,0,0};
  #pragma unroll
  for (int sp=0; sp<4; ++sp){
    cA = f4add(cA, *reinterpret_cast<const float4*>(colAp + (((size_t)sp*Bsz + b)*Nn + t)*Rr));
    cC = f4add(cC, *reinterpret_cast<const float4*>(colCp + (((size_t)sp*Bsz + b)*Nn + t)*Rr));
  }
  float4 Pv = *reinterpret_cast<const float4*>(P_ws + b*Rr);
  float4 Qv = *reinterpret_cast<const float4*>(Q_ws + b*Rr);
  float fwdv[4], bwdv[4];
  fwdv[0] = (1.0f-ww)*rA.x - rC.x + ww*Pv.x - Lnn*wr4.x;
  fwdv[1] = (1.0f-ww)*rA.y - rC.y + ww*Pv.y - Lnn*wr4.y;
  fwdv[2] = (1.0f-ww)*rA.z - rC.z + ww*Pv.z - Lnn*wr4.z;
  fwdv[3] = (1.0f-ww)*rA.w - rC.w + ww*Pv.w - Lnn*wr4.w;
  bwdv[0] = (1.0f-ww)*cA.x - cC.x + pr*Qv.x - Lnn*wr4.x;
  bwdv[1] = (1.0f-ww)*cA.y - cC.y + pr*Qv.y - Lnn*wr4.y;
  bwdv[2] = (1.0f-ww)*cA.z - cC.z + pr*Qv.z - Lnn*wr4.z;
  bwdv[3] = (1.0f-ww)*cA.w - cC.w + pr*Qv.w - Lnn*wr4.w;
  const float* Mrow = M + ((size_t)b*Nn + t)*Ww;
  float s0=0,s1=0,s2=0,s3=0, nrm=0;
  #pragma unroll 4
  for (int w=0;w<Ww;w+=4){
    float4 m4 = *reinterpret_cast<const float4*>(Mrow + w);
    float mvs[4] = {m4.x, m4.y, m4.z, m4.w};
    #pragma unroll
    for (int i=0;i<4;++i){
      int w_ = w+i;
      float mn = mvs[i]*(1.0f - ww*erl[w_]) + ww*wvl[w_];
      nrm += mn*mn;
      float4 k4 = *reinterpret_cast<const float4*>(&rkl[w_*4]);
      s0 += mn*k4.x; s1 += mn*k4.y; s2 += mn*k4.z; s3 += mn*k4.w;
    }
  }
  float mnorm = sqrtf(nrm);
  float4 kn = *reinterpret_cast<const float4*>(krn_ws + b*Rr);
  float4 rs = *reinterpret_cast<const float4*>(rstr_ws + b*Rr);
  float4 aa4;
  aa4.x = rs.x*(s0/(mnorm*kn.x + 1e-6f));
  aa4.y = rs.y*(s1/(mnorm*kn.y + 1e-6f));
  aa4.z = rs.z*(s2/(mnorm*kn.z + 1e-6f));
  aa4.w = rs.w*(s3/(mnorm*kn.w + 1e-6f));
  red4[t] = aa4; __syncthreads();
  for (int st=128; st>0; st>>=1){ if (t<st) red4[t] = f4max(red4[t], red4[t+st]); __syncthreads(); }
  float4 mx4 = red4[0]; __syncthreads();
  float4 e4;
  e4.x = expf(aa4.x - mx4.x); e4.y = expf(aa4.y - mx4.y);
  e4.z = expf(aa4.z - mx4.z); e4.w = expf(aa4.w - mx4.w);
  red4[t] = e4; __syncthreads();
  for (int st=128; st>0; st>>=1){ if (t<st) red4[t] = f4add(red4[t], red4[t+st]); __syncthreads(); }
  float4 sm4 = red4[0];
  float cr[4] = {e4.x/sm4.x, e4.y/sm4.y, e4.z/sm4.z, e4.w/sm4.w};
  float wro[4];
  #pragma unroll
  for (int r=0;r<4;++r){
    float m0 = rm_ws[b*12 + r];
    float m1 = rm_ws[b*12 + 4 + r];
    float m2 = rm_ws[b*12 + 8 + r];
    wro[r] = m0*bwdv[r] + m1*cr[r] + m2*fwdv[r];
  }
  wrl[t][0]=wro[0]; wrl[t][1]=wro[1]; wrl[t][2]=wro[2]; wrl[t][3]=wro[3];
  __syncthreads();
  {
    const int w = t & 63, r = t >> 6;
    const float er_w = erl[w], wv_w = wvl[w];
    float acc = 0.0f;
    #pragma unroll 4
    for (int n=0;n<Nn;++n){
      float m = M[((size_t)b*Nn + n)*Ww + w];
      float wwn = wwl[n];
      float mn = m*(1.0f - wwn*er_w) + wwn*wv_w;
      acc += mn*wrl[n][r];
    }
    rv_ws[(size_t)b*(Ww*Rr) + w*Rr + r] = acc;
  }
}

// ---------------- K5: output GEMM ------------------------------------------
__global__ __launch_bounds__(256) void k_final(
  const float* __restrict__ h_ws, const float* __restrict__ rv_ws,
  const float* __restrict__ Wo, const float* __restrict__ bo,
  float* __restrict__ out)
{
  const int t = threadIdx.x;
  const int tx = t & 15, ty = t >> 4;
  const int b0 = blockIdx.x*16;
  const int col = blockIdx.y*64 + tx*4;
  __shared__ float Cs[16][68];
  float4 acc = {0,0,0,0};
  for (int kc = 0; kc < 512; kc += 64){
    {
      int rr = t >> 4, cc = (t & 15)*4;
      const float* src = (kc < Uu)
        ? (h_ws  + (size_t)(b0+rr)*Uu + kc + cc)
        : (rv_ws + (size_t)(b0+rr)*(Ww*Rr) + (kc-Uu) + cc);
      *reinterpret_cast<float4*>(&Cs[rr][cc]) = *reinterpret_cast<const float4*>(src);
    }
    __syncthreads();
    const float* Wp = Wo + (size_t)kc*OUTsz + col;
    #pragma unroll 8
    for (int kk=0; kk<64; ++kk){
      float4 w4 = *reinterpret_cast<const float4*>(Wp + (size_t)kk*OUTsz);
      acc = f4fma(Cs[ty][kk], w4, acc);
    }
    __syncthreads();
  }
  float4 b4 = *reinterpret_cast<const float4*>(bo + col);
  acc.x = fminf(fmaxf(acc.x + b4.x, -20.0f), 20.0f);
  acc.y = fminf(fmaxf(acc.y + b4.y, -20.0f), 20.0f);
  acc.z = fminf(fmaxf(acc.z + b4.z, -20.0f), 20.0f);
  acc.w = fminf(fmaxf(acc.w + b4.w, -20.0f), 20.0f);
  *reinterpret_cast<float4*>(out + (size_t)(b0+ty)*OUTsz + col) = acc;
}

extern "C" void kernel_launch(void* const* d_in, const int* in_sizes, int n_in,
                              void* d_out, int out_size, void* d_ws, size_t ws_size,
                              hipStream_t stream)
{
  const float* inputs = (const float*)d_in[0];
  const float* M      = (const float*)d_in[1];
  const float* usage  = (const float*)d_in[2];
  const float* link   = (const float*)d_in[3];
  const float* prec   = (const float*)d_in[4];
  const float* wwp    = (const float*)d_in[5];
  const float* wrp    = (const float*)d_in[6];
  const float* hp     = (const float*)d_in[7];
  const float* cp     = (const float*)d_in[8];
  const float* rvp    = (const float*)d_in[9];
  const float* Wk     = (const float*)d_in[10];
  const float* Wr     = (const float*)d_in[11];
  const float* bl     = (const float*)d_in[12];
  const float* Wi     = (const float*)d_in[13];
  const float* bi     = (const float*)d_in[14];
  const float* Wo     = (const float*)d_in[15];
  const float* bo     = (const float*)d_in[16];

  float* ws = (float*)d_ws;
  float* X_ws    = ws;                                  // 512*640
  float* Wip     = X_ws   + (size_t)Bsz*KL;             // 256*512
  float* v_ws    = Wip    + (size_t)Uu*512;             // 512*512
  float* h_ws    = v_ws   + (size_t)Bsz*512;            // 512*256
  float* ww_ws   = h_ws   + (size_t)Bsz*Uu;
  float* er_ws   = ww_ws  + (size_t)Bsz*Nn;
  float* wv_ws   = er_ws  + (size_t)Bsz*Ww;
  float* rk_ws   = wv_ws  + (size_t)Bsz*Ww;
  float* krn_ws  = rk_ws  + (size_t)Bsz*Ww*Rr;
  float* rstr_ws = krn_ws + (size_t)Bsz*Rr;
  float* rm_ws   = rstr_ws+ (size_t)Bsz*Rr;
  float* P_ws    = rm_ws  + (size_t)Bsz*3*Rr;
  float* Q_ws    = P_ws   + (size_t)Bsz*Rr;
  float* rowA    = Q_ws   + (size_t)Bsz*Rr;
  float* rowC    = rowA   + (size_t)Bsz*Nn*Rr;
  float* colAp   = rowC   + (size_t)Bsz*Nn*Rr;          // 4 * B*N*R
  float* colCp   = colAp  + (size_t)4*Bsz*Nn*Rr;        // 4 * B*N*R
  float* diag    = colCp  + (size_t)4*Bsz*Nn*Rr;
  float* rv_ws   = diag   + (size_t)Bsz*Nn;

  k_pack<<<dim3(Bsz + Uu), dim3(256), 0, stream>>>(inputs, rvp, hp, Wi, X_ws, Wip);
  k_lstm<<<dim3(32,8), dim3(512), 0, stream>>>(X_ws, Wk, Wr, bl, cp, h_ws);
  k_ifgemm<<<dim3(32,8), dim3(256), 0, stream>>>(h_ws, Wip, v_ws);
  k_iface2<<<dim3(Bsz), dim3(256), 0, stream>>>(v_ws, bi, usage, wwp, wrp, prec, M,
      ww_ws, er_ws, wv_ws, rk_ws, krn_ws, rstr_ws, rm_ws, P_ws, Q_ws);
  k_link<<<dim3(Bsz,4), dim3(256), 0, stream>>>(link, wrp, ww_ws, rowA, rowC, colAp, colCp, diag);
  k_readw_rv<<<dim3(Bsz), dim3(256), 0, stream>>>(M, ww_ws, er_ws, wv_ws, rk_ws, krn_ws,
      rstr_ws, rm_ws, P_ws, Q_ws, rowA, rowC, colAp, colCp, diag, wrp, prec, rv_ws);
  k_final<<<dim3(32,2), dim3(256), 0, stream>>>(h_ws, rv_ws, Wo, bo, (float*)d_out);
}

// Round 5
// 188.378 us; speedup vs baseline: 1.3865x; 1.1928x over previous
//
#include <hip/hip_runtime.h>
#include <math.h>

#define Bsz 512
#define INsz 128
#define Nn 256
#define Ww 64
#define Rr 4
#define Uu 256
#define OUTsz 128
#define IFACEsz 471
#define XDIM 384   /* IN + W*R */
#define KL 640     /* XDIM + U */
#define G4 1024    /* 4*U */

__device__ __forceinline__ float sigf(float x){ return 1.0f/(1.0f+expf(-x)); }
__device__ __forceinline__ float softplusf_(float x){ return fmaxf(x,0.0f) + log1pf(expf(-fabsf(x))); }
__device__ __forceinline__ float4 f4fma(float s, float4 a, float4 acc){
  acc.x += s*a.x; acc.y += s*a.y; acc.z += s*a.z; acc.w += s*a.w; return acc;
}
__device__ __forceinline__ float4 f4add(float4 a, float4 b){
  a.x+=b.x; a.y+=b.y; a.z+=b.z; a.w+=b.w; return a;
}
__device__ __forceinline__ float4 f4max(float4 a, float4 b){
  a.x=fmaxf(a.x,b.x); a.y=fmaxf(a.y,b.y); a.z=fmaxf(a.z,b.z); a.w=fmaxf(a.w,b.w); return a;
}

// ---------------- K0: pad Wi to 512 cols -----------------------------------
__global__ __launch_bounds__(256) void k_packWi(
  const float* __restrict__ Wi, float* __restrict__ Wip)
{
  const int k = blockIdx.x, t = threadIdx.x;
  const int j2 = t + 256;
  Wip[(size_t)k*512 + t]  = Wi[(size_t)k*IFACEsz + t];
  Wip[(size_t)k*512 + j2] = (j2 < IFACEsz) ? Wi[(size_t)k*IFACEsz + j2] : 0.0f;
}

// ---------------- K1: LSTM GEMM + epilogue fused (inline X concat) ---------
// grid (32 batch-tiles, 8 col-groups of 32 units), 512 threads.
__global__ __launch_bounds__(512) void k_lstm(
  const float* __restrict__ inputs, const float* __restrict__ rvp,
  const float* __restrict__ hp, const float* __restrict__ Wk,
  const float* __restrict__ Wr, const float* __restrict__ bl,
  const float* __restrict__ cprev, float* __restrict__ h_out)
{
  const int t = threadIdx.x;
  const int tx = t & 7;          // col-quad within the 32-col group
  const int tg = (t >> 3) & 3;   // gate
  const int tb = t >> 5;         // batch 0..15
  const int b0 = blockIdx.x * 16;
  const int cg = blockIdx.y * 32;        // unit index base
  const int col = tg*256 + cg + tx*4;    // column in 1024
  __shared__ float Xs[16][68];
  __shared__ float zs[16][4][36];
  float4 acc = {0,0,0,0};
  for (int kc = 0; kc < KL; kc += 64){
    if (t < 256){
      const int rr = t >> 4, cc = (t & 15)*4;
      const int c = kc + cc;
      const float* src;
      if (c < INsz)      src = inputs + (size_t)(b0+rr)*INsz + c;
      else if (c < XDIM) src = rvp + (size_t)(b0+rr)*(Ww*Rr) + (c - INsz);
      else               src = hp + (size_t)(b0+rr)*Uu + (c - XDIM);
      *reinterpret_cast<float4*>(&Xs[rr][cc]) = *reinterpret_cast<const float4*>(src);
    }
    __syncthreads();
    const float* Wp = ((kc < XDIM) ? (Wk + (size_t)kc*G4) : (Wr + (size_t)(kc-XDIM)*G4)) + col;
    #pragma unroll 8
    for (int kk=0; kk<64; ++kk){
      float4 w4 = *reinterpret_cast<const float4*>(Wp + (size_t)kk*G4);
      acc = f4fma(Xs[tb][kk], w4, acc);
    }
    __syncthreads();
  }
  {
    float4 b4 = *reinterpret_cast<const float4*>(bl + col);
    acc = f4add(acc, b4);
  }
  *reinterpret_cast<float4*>(&zs[tb][tg][tx*4]) = acc;
  __syncthreads();
  {
    const int b = t >> 5, c = t & 31;
    float zi = zs[b][0][c], zf = zs[b][1][c], zc_ = zs[b][2][c], zo = zs[b][3][c];
    float cc = sigf(zf)*cprev[(size_t)(b0+b)*Uu + cg + c] + sigf(zi)*tanhf(zc_);
    float h = sigf(zo)*tanhf(cc);
    h = fminf(fmaxf(h,-20.0f),20.0f);
    h_out[(size_t)(b0+b)*Uu + cg + c] = h;
  }
}

// ---------------- K2a: interface GEMM v = h * Wip --------------------------
__global__ __launch_bounds__(256) void k_ifgemm(
  const float* __restrict__ h_ws, const float* __restrict__ Wip, float* __restrict__ v_ws)
{
  const int t = threadIdx.x;
  const int tx = t & 15, ty = t >> 4;
  const int b0 = blockIdx.x*16;
  const int col = blockIdx.y*64 + tx*4;
  __shared__ float Hs[16][68];
  float4 acc = {0,0,0,0};
  for (int kc = 0; kc < Uu; kc += 64){
    {
      int rr = t >> 4, cc = (t & 15)*4;
      *reinterpret_cast<float4*>(&Hs[rr][cc]) =
        *reinterpret_cast<const float4*>(h_ws + (size_t)(b0+rr)*Uu + kc + cc);
    }
    __syncthreads();
    const float* Wp = Wip + (size_t)kc*512 + col;
    #pragma unroll 8
    for (int kk=0; kk<64; ++kk){
      float4 w4 = *reinterpret_cast<const float4*>(Wp + (size_t)kk*512);
      acc = f4fma(Hs[ty][kk], w4, acc);
    }
    __syncthreads();
  }
  *reinterpret_cast<float4*>(v_ws + (size_t)(b0+ty)*512 + col) = acc;
}

// ---------------- K2b: interface logic -------------------------------------
__global__ __launch_bounds__(256) void k_iface2(
  const float* __restrict__ v_ws, const float* __restrict__ bi,
  const float* __restrict__ usage, const float* __restrict__ wwp,
  const float* __restrict__ wrp, const float* __restrict__ prec,
  const float* __restrict__ M,
  float* __restrict__ ww_ws, float* __restrict__ er_ws, float* __restrict__ wv_ws,
  float* __restrict__ rk_ws, float* __restrict__ krn_ws, float* __restrict__ rstr_ws,
  float* __restrict__ rm_ws, float* __restrict__ P_ws, float* __restrict__ Q_ws)
{
  const int b = blockIdx.x, t = threadIdx.x;
  __shared__ float vl[IFACEsz];
  __shared__ float wkey[Ww];
  __shared__ float ul[Nn], sul[Nn], cpl[Nn], red[Nn];
  __shared__ __align__(16) float4 red4[Nn];
  __shared__ float scal[8];
  for (int j=t; j<IFACEsz; j+=256) vl[j] = v_ws[(size_t)b*512 + j] + bi[j];
  __syncthreads();
  if (t < Ww){
    wkey[t] = vl[260+t];
    er_ws[b*Ww+t] = sigf(vl[325+t]);
    wv_ws[b*Ww+t] = vl[389+t];
  }
  rk_ws[b*Ww*Rr + t] = vl[t];
  if (t < Rr){
    rstr_ws[b*Rr+t] = 1.0f + softplusf_(vl[256+t]);
    float ssum = 0.0f;
    for (int w=0;w<Ww;++w){ float v = vl[w*Rr+t]; ssum += v*v; }
    krn_ws[b*Rr+t] = sqrtf(ssum);
    float q0=vl[459+t], q1=vl[463+t], q2=vl[467+t];
    float mm = fmaxf(q0, fmaxf(q1,q2));
    float e0=expf(q0-mm), e1=expf(q1-mm), e2=expf(q2-mm);
    float inv = 1.0f/(e0+e1+e2);
    rm_ws[b*12 + t]     = e0*inv;
    rm_ws[b*12 + 4 + t] = e1*inv;
    rm_ws[b*12 + 8 + t] = e2*inv;
    scal[4+t] = sigf(vl[453+t]);
  }
  if (t == 0){
    scal[0] = 1.0f + softplusf_(vl[324]);
    scal[1] = sigf(vl[457]);
    scal[2] = sigf(vl[458]);
    float ssum=0.0f;
    for (int w=0;w<Ww;++w){ float v=vl[260+w]; ssum += v*v; }
    scal[3] = sqrtf(ssum);
  }
  __syncthreads();
  float4 wr4 = *reinterpret_cast<const float4*>(wrp + ((size_t)b*Nn + t)*Rr);
  float psi = (1.0f - scal[4]*wr4.x)*(1.0f - scal[5]*wr4.y)
            * (1.0f - scal[6]*wr4.z)*(1.0f - scal[7]*wr4.w);
  float us = usage[b*Nn+t], wp = wwp[b*Nn+t];
  float u = (us + wp - us*wp)*psi;
  ul[t] = u;
  __syncthreads();
  int rank = 0;
  for (int m=0;m<Nn;++m){
    float um = ul[m];
    rank += (um < u || (um == u && m < t)) ? 1 : 0;
  }
  sul[rank] = u;
  __syncthreads();
  cpl[t] = sul[t];
  __syncthreads();
  for (int d=1; d<Nn; d<<=1){
    float a = cpl[t];
    float m_ = (t >= d) ? cpl[t-d] : 1.0f;
    __syncthreads();
    cpl[t] = a*m_;
    __syncthreads();
  }
  float cpexcl = (rank == 0) ? 1.0f : cpl[rank-1];
  float alloc = (1.0f - u)*cpexcl;
  const float* Mrow = M + ((size_t)b*Nn + t)*Ww;
  float dot=0.0f, nrm=0.0f;
  #pragma unroll 4
  for (int w=0;w<Ww;w+=4){
    float4 m4 = *reinterpret_cast<const float4*>(Mrow + w);
    dot += m4.x*wkey[w] + m4.y*wkey[w+1] + m4.z*wkey[w+2] + m4.w*wkey[w+3];
    nrm += m4.x*m4.x + m4.y*m4.y + m4.z*m4.z + m4.w*m4.w;
  }
  float sim = dot/(sqrtf(nrm)*scal[3] + 1e-6f);
  float sc = scal[0]*sim;
  red[t] = sc; __syncthreads();
  for (int st=128; st>0; st>>=1){ if (t<st) red[t] = fmaxf(red[t], red[t+st]); __syncthreads(); }
  float mx = red[0]; __syncthreads();
  float e = expf(sc - mx);
  red[t] = e; __syncthreads();
  for (int st=128; st>0; st>>=1){ if (t<st) red[t] += red[t+st]; __syncthreads(); }
  float cw = e/red[0];
  float ww = scal[2]*(scal[1]*alloc + (1.0f - scal[1])*cw);
  ww_ws[b*Nn+t] = ww;
  __syncthreads();
  float pr = prec[b*Nn+t];
  float4 pv; pv.x = pr*wr4.x; pv.y = pr*wr4.y; pv.z = pr*wr4.z; pv.w = pr*wr4.w;
  red4[t] = pv; __syncthreads();
  for (int st=128; st>0; st>>=1){ if (t<st) red4[t] = f4add(red4[t], red4[t+st]); __syncthreads(); }
  if (t==0) *reinterpret_cast<float4*>(P_ws + b*Rr) = red4[0];
  __syncthreads();
  float4 qv; qv.x = ww*wr4.x; qv.y = ww*wr4.y; qv.z = ww*wr4.z; qv.w = ww*wr4.w;
  red4[t] = qv; __syncthreads();
  for (int st=128; st>0; st>>=1){ if (t<st) red4[t] = f4add(red4[t], red4[t+st]); __syncthreads(); }
  if (t==0) *reinterpret_cast<float4*>(Q_ws + b*Rr) = red4[0];
}

// ---------------- K3: link products, register-only two-phase ---------------
// grid (B, 4): strip of 64 rows. Phase A: col partials (coalesced stream,
// thread = column). Phase B: row products from the now L1/L2-hot strip
// (4 threads/row, 16 independent float4 loads, width-4 shfl reduce).
__global__ __launch_bounds__(256) void k_link(
  const float* __restrict__ link, const float* __restrict__ wrp,
  const float* __restrict__ ww_ws,
  float* __restrict__ rowA, float* __restrict__ rowC,
  float* __restrict__ colAp, float* __restrict__ colCp, float* __restrict__ diag)
{
  const int b = blockIdx.x, s = blockIdx.y, t = threadIdx.x;
  const int n0 = s*64;
  __shared__ __align__(16) float4 wrl4[Nn];
  __shared__ __align__(16) float wws[Nn];
  wrl4[t] = *reinterpret_cast<const float4*>(wrp + ((size_t)b*Nn + t)*Rr);
  wws[t]  = ww_ws[(size_t)b*Nn + t];
  __syncthreads();
  const float* Lb = link + (size_t)b*Nn*Nn;
  // ---- Phase A: col partials over strip rows, thread = column t
  {
    float4 cA = {0,0,0,0}, cC = {0,0,0,0};
    float dg = 0.0f;
    #pragma unroll 4
    for (int i=0;i<64;++i){
      const int n = n0 + i;
      float l = Lb[(size_t)n*Nn + t];
      float4 wn = wrl4[n];
      cA = f4fma(l, wn, cA);
      cC = f4fma(l*wws[n], wn, cC);
      if (n == t) dg = l;
    }
    *reinterpret_cast<float4*>(colAp + (((size_t)s*Bsz + b)*Nn + t)*Rr) = cA;
    *reinterpret_cast<float4*>(colCp + (((size_t)s*Bsz + b)*Nn + t)*Rr) = cC;
    if (t >= n0 && t < n0+64) diag[(size_t)b*Nn + t] = dg;
  }
  // ---- Phase B: row products, 4 threads per row (seg = 64-col chunk)
  {
    const int row = n0 + (t >> 2), seg = t & 3;
    const float* Lr = Lb + (size_t)row*Nn + seg*64;
    float ra0=0,ra1=0,ra2=0,ra3=0, rc0=0,rc1=0,rc2=0,rc3=0;
    #pragma unroll
    for (int k=0;k<16;++k){
      float4 l4 = *reinterpret_cast<const float4*>(Lr + k*4);
      const int m0 = seg*64 + k*4;
      float4 ww4 = *reinterpret_cast<const float4*>(&wws[m0]);
      float4 w0 = wrl4[m0], w1 = wrl4[m0+1], w2 = wrl4[m0+2], w3 = wrl4[m0+3];
      ra0 += l4.x*w0.x + l4.y*w1.x + l4.z*w2.x + l4.w*w3.x;
      ra1 += l4.x*w0.y + l4.y*w1.y + l4.z*w2.y + l4.w*w3.y;
      ra2 += l4.x*w0.z + l4.y*w1.z + l4.z*w2.z + l4.w*w3.z;
      ra3 += l4.x*w0.w + l4.y*w1.w + l4.z*w2.w + l4.w*w3.w;
      float lx=l4.x*ww4.x, ly=l4.y*ww4.y, lz=l4.z*ww4.z, lw=l4.w*ww4.w;
      rc0 += lx*w0.x + ly*w1.x + lz*w2.x + lw*w3.x;
      rc1 += lx*w0.y + ly*w1.y + lz*w2.y + lw*w3.y;
      rc2 += lx*w0.z + ly*w1.z + lz*w2.z + lw*w3.z;
      rc3 += lx*w0.w + ly*w1.w + lz*w2.w + lw*w3.w;
    }
    #pragma unroll
    for (int off=2; off>=1; off>>=1){
      ra0 += __shfl_down(ra0, off, 4); ra1 += __shfl_down(ra1, off, 4);
      ra2 += __shfl_down(ra2, off, 4); ra3 += __shfl_down(ra3, off, 4);
      rc0 += __shfl_down(rc0, off, 4); rc1 += __shfl_down(rc1, off, 4);
      rc2 += __shfl_down(rc2, off, 4); rc3 += __shfl_down(rc3, off, 4);
    }
    if (seg == 0){
      float4 oA; oA.x=ra0; oA.y=ra1; oA.z=ra2; oA.w=ra3;
      float4 oC; oC.x=rc0; oC.y=rc1; oC.z=rc2; oC.w=rc3;
      *reinterpret_cast<float4*>(rowA + ((size_t)b*Nn + row)*Rr) = oA;
      *reinterpret_cast<float4*>(rowC + ((size_t)b*Nn + row)*Rr) = oC;
    }
  }
}

// ---------------- K4: fwd/bwd + read addressing + wr + read vectors --------
__global__ __launch_bounds__(256) void k_readw_rv(
  const float* __restrict__ M, const float* __restrict__ ww_ws,
  const float* __restrict__ er_ws, const float* __restrict__ wv_ws,
  const float* __restrict__ rk_ws, const float* __restrict__ krn_ws,
  const float* __restrict__ rstr_ws, const float* __restrict__ rm_ws,
  const float* __restrict__ P_ws, const float* __restrict__ Q_ws,
  const float* __restrict__ rowA, const float* __restrict__ rowC,
  const float* __restrict__ colAp, const float* __restrict__ colCp,
  const float* __restrict__ diag, const float* __restrict__ wrp,
  const float* __restrict__ prec, float* __restrict__ rv_ws)
{
  const int b = blockIdx.x, t = threadIdx.x;
  __shared__ float rkl[Ww*Rr];
  __shared__ float erl[Ww], wvl[Ww];
  __shared__ __align__(16) float4 red4[Nn];
  __shared__ float wrl[Nn][4];
  __shared__ float wwl[Nn];
  rkl[t] = rk_ws[b*Ww*Rr + t];
  if (t < Ww){ erl[t] = er_ws[b*Ww+t]; wvl[t] = wv_ws[b*Ww+t]; }
  const float ww = ww_ws[b*Nn+t];
  wwl[t] = ww;
  __syncthreads();
  const float pr = prec[b*Nn+t];
  const float dg = diag[b*Nn+t];
  float4 wr4 = *reinterpret_cast<const float4*>(wrp + ((size_t)b*Nn+t)*Rr);
  const float Lnn = (1.0f - 2.0f*ww)*dg + ww*pr;
  float4 rA = *reinterpret_cast<const float4*>(rowA + ((size_t)b*Nn+t)*Rr);
  float4 rC = *reinterpret_cast<const float4*>(rowC + ((size_t)b*Nn+t)*Rr);
  float4 cA = {0,0,0,0}, cC = {0,0,0,0};
  #pragma unroll
  for (int sp=0; sp<4; ++sp){
    cA = f4add(cA, *reinterpret_cast<const float4*>(colAp + (((size_t)sp*Bsz + b)*Nn + t)*Rr));
    cC = f4add(cC, *reinterpret_cast<const float4*>(colCp + (((size_t)sp*Bsz + b)*Nn + t)*Rr));
  }
  float4 Pv = *reinterpret_cast<const float4*>(P_ws + b*Rr);
  float4 Qv = *reinterpret_cast<const float4*>(Q_ws + b*Rr);
  float fwdv[4], bwdv[4];
  fwdv[0] = (1.0f-ww)*rA.x - rC.x + ww*Pv.x - Lnn*wr4.x;
  fwdv[1] = (1.0f-ww)*rA.y - rC.y + ww*Pv.y - Lnn*wr4.y;
  fwdv[2] = (1.0f-ww)*rA.z - rC.z + ww*Pv.z - Lnn*wr4.z;
  fwdv[3] = (1.0f-ww)*rA.w - rC.w + ww*Pv.w - Lnn*wr4.w;
  bwdv[0] = (1.0f-ww)*cA.x - cC.x + pr*Qv.x - Lnn*wr4.x;
  bwdv[1] = (1.0f-ww)*cA.y - cC.y + pr*Qv.y - Lnn*wr4.y;
  bwdv[2] = (1.0f-ww)*cA.z - cC.z + pr*Qv.z - Lnn*wr4.z;
  bwdv[3] = (1.0f-ww)*cA.w - cC.w + pr*Qv.w - Lnn*wr4.w;
  const float* Mrow = M + ((size_t)b*Nn + t)*Ww;
  float s0=0,s1=0,s2=0,s3=0, nrm=0;
  #pragma unroll 4
  for (int w=0;w<Ww;w+=4){
    float4 m4 = *reinterpret_cast<const float4*>(Mrow + w);
    float mvs[4] = {m4.x, m4.y, m4.z, m4.w};
    #pragma unroll
    for (int i=0;i<4;++i){
      int w_ = w+i;
      float mn = mvs[i]*(1.0f - ww*erl[w_]) + ww*wvl[w_];
      nrm += mn*mn;
      float4 k4 = *reinterpret_cast<const float4*>(&rkl[w_*4]);
      s0 += mn*k4.x; s1 += mn*k4.y; s2 += mn*k4.z; s3 += mn*k4.w;
    }
  }
  float mnorm = sqrtf(nrm);
  float4 kn = *reinterpret_cast<const float4*>(krn_ws + b*Rr);
  float4 rs = *reinterpret_cast<const float4*>(rstr_ws + b*Rr);
  float4 aa4;
  aa4.x = rs.x*(s0/(mnorm*kn.x + 1e-6f));
  aa4.y = rs.y*(s1/(mnorm*kn.y + 1e-6f));
  aa4.z = rs.z*(s2/(mnorm*kn.z + 1e-6f));
  aa4.w = rs.w*(s3/(mnorm*kn.w + 1e-6f));
  red4[t] = aa4; __syncthreads();
  for (int st=128; st>0; st>>=1){ if (t<st) red4[t] = f4max(red4[t], red4[t+st]); __syncthreads(); }
  float4 mx4 = red4[0]; __syncthreads();
  float4 e4;
  e4.x = expf(aa4.x - mx4.x); e4.y = expf(aa4.y - mx4.y);
  e4.z = expf(aa4.z - mx4.z); e4.w = expf(aa4.w - mx4.w);
  red4[t] = e4; __syncthreads();
  for (int st=128; st>0; st>>=1){ if (t<st) red4[t] = f4add(red4[t], red4[t+st]); __syncthreads(); }
  float4 sm4 = red4[0];
  float cr[4] = {e4.x/sm4.x, e4.y/sm4.y, e4.z/sm4.z, e4.w/sm4.w};
  float wro[4];
  #pragma unroll
  for (int r=0;r<4;++r){
    float m0 = rm_ws[b*12 + r];
    float m1 = rm_ws[b*12 + 4 + r];
    float m2 = rm_ws[b*12 + 8 + r];
    wro[r] = m0*bwdv[r] + m1*cr[r] + m2*fwdv[r];
  }
  wrl[t][0]=wro[0]; wrl[t][1]=wro[1]; wrl[t][2]=wro[2]; wrl[t][3]=wro[3];
  __syncthreads();
  // read vectors: thread = (w, r); 4 accumulators for MLP
  {
    const int w = t & 63, r = t >> 6;
    const float er_w = erl[w], wv_w = wvl[w];
    float a0=0.0f, a1=0.0f, a2=0.0f, a3=0.0f;
    for (int n=0;n<Nn;n+=4){
      float m0v = M[((size_t)b*Nn + n  )*Ww + w];
      float m1v = M[((size_t)b*Nn + n+1)*Ww + w];
      float m2v = M[((size_t)b*Nn + n+2)*Ww + w];
      float m3v = M[((size_t)b*Nn + n+3)*Ww + w];
      float w0 = wwl[n], w1 = wwl[n+1], w2 = wwl[n+2], w3 = wwl[n+3];
      a0 += (m0v*(1.0f - w0*er_w) + w0*wv_w)*wrl[n  ][r];
      a1 += (m1v*(1.0f - w1*er_w) + w1*wv_w)*wrl[n+1][r];
      a2 += (m2v*(1.0f - w2*er_w) + w2*wv_w)*wrl[n+2][r];
      a3 += (m3v*(1.0f - w3*er_w) + w3*wv_w)*wrl[n+3][r];
    }
    rv_ws[(size_t)b*(Ww*Rr) + w*Rr + r] = (a0+a1)+(a2+a3);
  }
}

// ---------------- K5: output GEMM ------------------------------------------
__global__ __launch_bounds__(256) void k_final(
  const float* __restrict__ h_ws, const float* __restrict__ rv_ws,
  const float* __restrict__ Wo, const float* __restrict__ bo,
  float* __restrict__ out)
{
  const int t = threadIdx.x;
  const int tx = t & 15, ty = t >> 4;
  const int b0 = blockIdx.x*16;
  const int col = blockIdx.y*64 + tx*4;
  __shared__ float Cs[16][68];
  float4 acc = {0,0,0,0};
  for (int kc = 0; kc < 512; kc += 64){
    {
      int rr = t >> 4, cc = (t & 15)*4;
      const float* src = (kc < Uu)
        ? (h_ws  + (size_t)(b0+rr)*Uu + kc + cc)
        : (rv_ws + (size_t)(b0+rr)*(Ww*Rr) + (kc-Uu) + cc);
      *reinterpret_cast<float4*>(&Cs[rr][cc]) = *reinterpret_cast<const float4*>(src);
    }
    __syncthreads();
    const float* Wp = Wo + (size_t)kc*OUTsz + col;
    #pragma unroll 8
    for (int kk=0; kk<64; ++kk){
      float4 w4 = *reinterpret_cast<const float4*>(Wp + (size_t)kk*OUTsz);
      acc = f4fma(Cs[ty][kk], w4, acc);
    }
    __syncthreads();
  }
  float4 b4 = *reinterpret_cast<const float4*>(bo + col);
  acc.x = fminf(fmaxf(acc.x + b4.x, -20.0f), 20.0f);
  acc.y = fminf(fmaxf(acc.y + b4.y, -20.0f), 20.0f);
  acc.z = fminf(fmaxf(acc.z + b4.z, -20.0f), 20.0f);
  acc.w = fminf(fmaxf(acc.w + b4.w, -20.0f), 20.0f);
  *reinterpret_cast<float4*>(out + (size_t)(b0+ty)*OUTsz + col) = acc;
}

extern "C" void kernel_launch(void* const* d_in, const int* in_sizes, int n_in,
                              void* d_out, int out_size, void* d_ws, size_t ws_size,
                              hipStream_t stream)
{
  const float* inputs = (const float*)d_in[0];
  const float* M      = (const float*)d_in[1];
  const float* usage  = (const float*)d_in[2];
  const float* link   = (const float*)d_in[3];
  const float* prec   = (const float*)d_in[4];
  const float* wwp    = (const float*)d_in[5];
  const float* wrp    = (const float*)d_in[6];
  const float* hp     = (const float*)d_in[7];
  const float* cp     = (const float*)d_in[8];
  const float* rvp    = (const float*)d_in[9];
  const float* Wk     = (const float*)d_in[10];
  const float* Wr     = (const float*)d_in[11];
  const float* bl     = (const float*)d_in[12];
  const float* Wi     = (const float*)d_in[13];
  const float* bi     = (const float*)d_in[14];
  const float* Wo     = (const float*)d_in[15];
  const float* bo     = (const float*)d_in[16];

  float* ws = (float*)d_ws;
  float* Wip     = ws;                                  // 256*512
  float* v_ws    = Wip    + (size_t)Uu*512;             // 512*512
  float* h_ws    = v_ws   + (size_t)Bsz*512;            // 512*256
  float* ww_ws   = h_ws   + (size_t)Bsz*Uu;
  float* er_ws   = ww_ws  + (size_t)Bsz*Nn;
  float* wv_ws   = er_ws  + (size_t)Bsz*Ww;
  float* rk_ws   = wv_ws  + (size_t)Bsz*Ww;
  float* krn_ws  = rk_ws  + (size_t)Bsz*Ww*Rr;
  float* rstr_ws = krn_ws + (size_t)Bsz*Rr;
  float* rm_ws   = rstr_ws+ (size_t)Bsz*Rr;
  float* P_ws    = rm_ws  + (size_t)Bsz*3*Rr;
  float* Q_ws    = P_ws   + (size_t)Bsz*Rr;
  float* rowA    = Q_ws   + (size_t)Bsz*Rr;
  float* rowC    = rowA   + (size_t)Bsz*Nn*Rr;
  float* colAp   = rowC   + (size_t)Bsz*Nn*Rr;          // 4 * B*N*R
  float* colCp   = colAp  + (size_t)4*Bsz*Nn*Rr;        // 4 * B*N*R
  float* diag    = colCp  + (size_t)4*Bsz*Nn*Rr;
  float* rv_ws   = diag   + (size_t)Bsz*Nn;

  k_packWi<<<dim3(Uu), dim3(256), 0, stream>>>(Wi, Wip);
  k_lstm<<<dim3(32,8), dim3(512), 0, stream>>>(inputs, rvp, hp, Wk, Wr, bl, cp, h_ws);
  k_ifgemm<<<dim3(32,8), dim3(256), 0, stream>>>(h_ws, Wip, v_ws);
  k_iface2<<<dim3(Bsz), dim3(256), 0, stream>>>(v_ws, bi, usage, wwp, wrp, prec, M,
      ww_ws, er_ws, wv_ws, rk_ws, krn_ws, rstr_ws, rm_ws, P_ws, Q_ws);
  k_link<<<dim3(Bsz,4), dim3(256), 0, stream>>>(link, wrp, ww_ws, rowA, rowC, colAp, colCp, diag);
  k_readw_rv<<<dim3(Bsz), dim3(256), 0, stream>>>(M, ww_ws, er_ws, wv_ws, rk_ws, krn_ws,
      rstr_ws, rm_ws, P_ws, Q_ws, rowA, rowC, colAp, colCp, diag, wrp, prec, rv_ws);
  k_final<<<dim3(32,2), dim3(256), 0, stream>>>(h_ws, rv_ws, Wo, bo, (float*)d_out);
}